// Round 11
// baseline (4611.556 us; speedup 1.0000x reference)
//
#include <hip/hip_runtime.h>
#include <math.h>

#define DEVI static __device__ __forceinline__

typedef __attribute__((ext_vector_type(8))) short short8b;  // 8 bf16 (4 VGPR)
typedef __attribute__((ext_vector_type(4))) float f32x4;

DEVI float gelu_f(float x) { return 0.5f * x * (1.0f + erff(x * 0.70710678118654752440f)); }

// ---- 3-split bf16: x ~= b0 + b1 + b2 (each RN bf16); storage = 3 planes ----
DEVI unsigned pack2(float x)
{
    unsigned xb = __float_as_uint(x);
    unsigned hi = (xb + 0x7FFFu + ((xb >> 16) & 1u)) & 0xFFFF0000u;
    float lof = x - __uint_as_float(hi);
    unsigned lb = __float_as_uint(lof);
    unsigned lo = (lb + 0x7FFFu + ((lb >> 16) & 1u)) >> 16;
    return hi | lo;
}
DEVI float unpk(unsigned u)
{
    return __uint_as_float(u & 0xFFFF0000u) + __uint_as_float(u << 16);
}
DEVI unsigned bf16r(float x)
{
    unsigned b = __float_as_uint(x);
    return (b + 0x7FFFu + ((b >> 16) & 1u)) >> 16;
}
DEVI float bf2f(unsigned short u) { return __uint_as_float((unsigned)u << 16); }

// LDS plane row: 32 bf16 = 16 data u32 + 2 pad = 18 u32 stride (proven r4).
DEVI short8b ldfrag(const unsigned* P, int row, int kq)
{
    const unsigned* b = P + row * 18 + kq * 2;
    union { uint2 h[2]; short8b s; } r;
    r.h[0] = *(const uint2*)(b);
    r.h[1] = *(const uint2*)(b + 8);
    return r.s;
}
DEVI void st4(unsigned* b, uint4 v0)
{
    uint2 t;
    t.x = v0.x; t.y = v0.y; *(uint2*)(b) = t;
    t.x = v0.z; t.y = v0.w; *(uint2*)(b + 2) = t;
}

#define MFMA6(ACC, A0, A1, A2F, W0, W1, W2F) do { \
    ACC = __builtin_amdgcn_mfma_f32_16x16x32_bf16(A2F, W0, ACC, 0, 0, 0); \
    ACC = __builtin_amdgcn_mfma_f32_16x16x32_bf16(A0, W2F, ACC, 0, 0, 0); \
    ACC = __builtin_amdgcn_mfma_f32_16x16x32_bf16(A1, W1, ACC, 0, 0, 0); \
    ACC = __builtin_amdgcn_mfma_f32_16x16x32_bf16(A1, W0, ACC, 0, 0, 0); \
    ACC = __builtin_amdgcn_mfma_f32_16x16x32_bf16(A0, W1, ACC, 0, 0, 0); \
    ACC = __builtin_amdgcn_mfma_f32_16x16x32_bf16(A0, W0, ACC, 0, 0, 0); \
} while (0)

// ---------------------------------------------------------------------------
// Direct 3x3 conv for small Cin (stem L0-L2) — r8-proven balance
// ---------------------------------------------------------------------------
template <int CIN, int NCO>
__global__ __launch_bounds__(256)
void conv3x3_t(const float* __restrict__ in, const float* __restrict__ w,
               const float* __restrict__ bias, float* __restrict__ out,
               int Cout, int Hin, int Win, int Hout, int Wout, int stride)
{
    __shared__ __align__(16) float wlds[CIN * 9 * NCO];
    int b = blockIdx.z;
    int co0 = blockIdx.y * NCO;
    int tid = threadIdx.x;
    int HWo = Hout * Wout;
    int s = blockIdx.x * 256 + tid;
    int sc = (s < HWo) ? s : (HWo - 1);
    int ho = sc / Wout, wo = sc % Wout;
    float acc[NCO];
#pragma unroll
    for (int j = 0; j < NCO; j++) acc[j] = bias[co0 + j];
    const float* inb = in + (size_t)b * CIN * Hin * Win;
    size_t HWi = (size_t)Hin * Win;

    const int nw = NCO * CIN * 9;
    for (int i = tid; i < nw; i += 256) {
        int j = i % NCO;
        int rest = i / NCO;
        int ci = rest % CIN, tap = rest / CIN;
        wlds[i] = w[((size_t)(co0 + j) * CIN + ci) * 9 + tap];
    }
    __syncthreads();
    for (int kh = 0; kh < 3; kh++) {
        int hi = ho * stride - 1 + kh;
        bool okh = (hi >= 0 && hi < Hin);
        for (int kw = 0; kw < 3; kw++) {
            int wi = wo * stride - 1 + kw;
            if (!okh || wi < 0 || wi >= Win) continue;
            int tap = kh * 3 + kw;
            const float* ip = inb + (size_t)hi * Win + wi;
            const float* wp = wlds + (size_t)tap * CIN * NCO;
#pragma unroll 4
            for (int ci = 0; ci < CIN; ci++) {
                float xv = ip[(size_t)ci * HWi];
                const float* wq = wp + ci * NCO;
#pragma unroll
                for (int j4 = 0; j4 < NCO; j4 += 4) {
                    float4 wv = *(const float4*)(wq + j4);
                    acc[j4 + 0] += xv * wv.x; acc[j4 + 1] += xv * wv.y;
                    acc[j4 + 2] += xv * wv.z; acc[j4 + 3] += xv * wv.w;
                }
            }
        }
    }
    if (s < HWo) {
        size_t ob = ((size_t)b * Cout + co0) * HWo + s;
#pragma unroll
        for (int j = 0; j < NCO; j++) out[ob + (size_t)j * HWo] = acc[j];
    }
}

// ---------------------------------------------------------------------------
// GroupNorm (deterministic) — unchanged
// ---------------------------------------------------------------------------
__global__ __launch_bounds__(256)
void gn_stats_k(const float* __restrict__ x, double* __restrict__ part,
                int C, int HW, int cpg, int S)
{
    int srt = blockIdx.x, g = blockIdx.y, b = blockIdx.z;
    long len = (long)cpg * HW;
    long chunk = (len + S - 1) / S;
    long lo = (long)srt * chunk;
    long hi = lo + chunk; if (hi > len) hi = len;
    const float* xp = x + ((size_t)b * C + (size_t)g * cpg) * HW;
    double s1 = 0.0, s2 = 0.0;
    for (long i = lo + threadIdx.x; i < hi; i += 256) {
        double v = (double)xp[i];
        s1 += v; s2 += v * v;
    }
    __shared__ double r1[256], r2[256];
    r1[threadIdx.x] = s1; r2[threadIdx.x] = s2;
    __syncthreads();
    for (int t = 128; t > 0; t >>= 1) {
        if (threadIdx.x < t) { r1[threadIdx.x] += r1[threadIdx.x + t]; r2[threadIdx.x] += r2[threadIdx.x + t]; }
        __syncthreads();
    }
    if (threadIdx.x == 0) {
        size_t slot = ((size_t)(b * 32 + g) * S + srt) * 2;
        part[slot] = r1[0];
        part[slot + 1] = r2[0];
    }
}

__global__ __launch_bounds__(64)
void gn_reduce_k(const double* __restrict__ part, float* __restrict__ fin,
                 int S, double cnt)
{
    int t = threadIdx.x;
    double s1 = 0.0, s2 = 0.0;
    for (int s = 0; s < S; s++) {
        size_t slot = ((size_t)t * S + s) * 2;
        s1 += part[slot];
        s2 += part[slot + 1];
    }
    double m = s1 / cnt;
    double var = s2 / cnt - m * m;
    double inv = 1.0 / sqrt(var + 1e-5);
    fin[t * 2] = (float)m;
    fin[t * 2 + 1] = (float)inv;
}

__global__ __launch_bounds__(256)
void gn_apply_k(float* __restrict__ x, const float* __restrict__ fin,
                const float* __restrict__ gma, const float* __restrict__ bta,
                int C, int HW, int cpg, int do_gelu, int total)
{
    int idx = blockIdx.x * 256 + threadIdx.x;
    if (idx >= total) return;
    int c = (idx / HW) % C;
    int b = idx / (HW * C);
    int g = c / cpg;
    float m = fin[(b * 32 + g) * 2];
    float inv = fin[(b * 32 + g) * 2 + 1];
    float v = (x[idx] - m) * inv * gma[c] + bta[c];
    if (do_gelu) v = gelu_f(v);
    x[idx] = v;
}

// ---------------------------------------------------------------------------
// Transpose+split stem input: in[b][c][hw] fp32 -> 3 planes [b][hw][c] bf16
// ---------------------------------------------------------------------------
__global__ __launch_bounds__(256)
void splitT_k(const float* __restrict__ in, unsigned short* __restrict__ P0,
              unsigned short* __restrict__ P1, unsigned short* __restrict__ P2,
              int C, int HW)
{
    __shared__ float tile[64][65];
    int h0 = blockIdx.x * 64, c0 = blockIdx.y * 64, b = blockIdx.z;
    int tid = threadIdx.x;
    int tl = tid & 63;
    const float* inb = in + (size_t)b * C * HW;
#pragma unroll
    for (int p = 0; p < 16; p++) {
        int c = (tid >> 6) + p * 4;
        int h = h0 + tl;
        tile[c][tl] = (h < HW) ? inb[(size_t)(c0 + c) * HW + h] : 0.f;
    }
    __syncthreads();
#pragma unroll
    for (int p = 0; p < 16; p++) {
        int hh = (tid >> 6) + p * 4;
        int h = h0 + hh;
        if (h >= HW) continue;
        int ch = c0 + tl;
        float v = tile[tl][hh];
        unsigned pm = pack2(v);
        size_t off = ((size_t)b * HW + h) * C + ch;
        P0[off] = (unsigned short)(pm >> 16);
        P1[off] = (unsigned short)(pm & 0xFFFFu);
        P2[off] = (unsigned short)bf16r(v - unpk(pm));
    }
}

// ---------------------------------------------------------------------------
// Conv weight pack to 3 planes, k = tap*Cin + ci — unchanged
// ---------------------------------------------------------------------------
__global__ __launch_bounds__(256)
void wconvp_k(const float* __restrict__ w, unsigned short* __restrict__ P0,
              unsigned short* __restrict__ P1, unsigned short* __restrict__ P2,
              int Cin, int total)
{
    int idx = blockIdx.x * 256 + threadIdx.x;
    if (idx >= total) return;
    int K = Cin * 9;
    int co = idx / K, k = idx % K;
    int tap = k / Cin, ci = k - tap * Cin;
    float v = w[((size_t)co * Cin + ci) * 9 + tap];
    unsigned pm = pack2(v);
    P0[idx] = (unsigned short)(pm >> 16);
    P1[idx] = (unsigned short)(pm & 0xFFFFu);
    P2[idx] = (unsigned short)bf16r(v - unpk(pm));
}

// ---------------------------------------------------------------------------
// Main-loop weight pack (fc1|mr|fc2|ffn1|ffn2) to 3 planes — unchanged
// ---------------------------------------------------------------------------
__global__ __launch_bounds__(256)
void pack5p_k(const float* __restrict__ s0, const float* __restrict__ s1,
              const float* __restrict__ s2, const float* __restrict__ s3,
              const float* __restrict__ s4, unsigned short* __restrict__ P0,
              unsigned short* __restrict__ P1, unsigned short* __restrict__ P2)
{
    int idx = blockIdx.x * 256 + threadIdx.x;   // grid exact: 983040
    float v;
    if (idx < 65536)       v = s0[idx];
    else if (idx < 327680) v = s1[idx - 65536];
    else if (idx < 458752) v = s2[idx - 327680];
    else if (idx < 720896) v = s3[idx - 458752];
    else                   v = s4[idx - 720896];
    unsigned pm = pack2(v);
    P0[idx] = (unsigned short)(pm >> 16);
    P1[idx] = (unsigned short)(pm & 0xFFFFu);
    P2[idx] = (unsigned short)bf16r(v - unpk(pm));
}

// ---------------------------------------------------------------------------
// MFMA GEMM, 6-term, plane storage, r11: BN=64 x BM=64, double-buffered LDS,
// ONE barrier per k-step (r6 schedule, now at occ-2: LDS 55.3KB).
// Waves 2x2 of 32x32. MFMA order identical to r10 -> numerics identical.
// ---------------------------------------------------------------------------
__global__ __launch_bounds__(256, 2)
void mgemm6p_k(const unsigned short* __restrict__ A0, const unsigned short* __restrict__ A1,
               const unsigned short* __restrict__ A2,
               const unsigned short* __restrict__ W0, const unsigned short* __restrict__ W1,
               const unsigned short* __restrict__ W2,
               const float* __restrict__ bias, const float* __restrict__ gma,
               const float* __restrict__ bta,
               const unsigned short* __restrict__ R0, const unsigned short* __restrict__ R1,
               const unsigned short* __restrict__ R2,
               unsigned short* __restrict__ C0, unsigned short* __restrict__ C1,
               unsigned short* __restrict__ C2,
               int N, int M, int K, int do_gelu)
{
    __shared__ __align__(16) unsigned lA[2][3][64 * 18];
    __shared__ __align__(16) unsigned lW[2][3][64 * 18];
    int bz = blockIdx.z;
    int n0 = blockIdx.x * 64, m0 = blockIdx.y * 64;
    int tid = threadIdx.x, wave = tid >> 6, lane = tid & 63;
    int wn = (wave & 1) * 32, wm = (wave >> 1) * 32;
    int rl = lane & 15, kq = lane >> 4;

    f32x4 acc[2][2] = {};

    const unsigned* Ag[3] = {(const unsigned*)A0, (const unsigned*)A1, (const unsigned*)A2};
    const unsigned* Wg[3] = {(const unsigned*)W0, (const unsigned*)W1, (const unsigned*)W2};

    int ar = tid >> 2, ah = tid & 3;
    int aga = n0 + ar; if (aga >= N) aga = N - 1;
    size_t abase = (((size_t)bz * N + aga) * K) >> 1;
    int aoff = ar * 18 + ah * 4;

    int wr_ = tid >> 2, wo_ = (tid & 3) * 4;
    size_t wbase = ((size_t)(m0 + wr_) * K) >> 1;
    int woff = wr_ * 18 + wo_;

    uint4 aA[3], aB[3], wA[3], wB[3];

    auto loadS = [&](int ks, uint4 (&da)[3], uint4 (&dw)[3]) {
#pragma unroll
        for (int pl = 0; pl < 3; pl++) {
            da[pl] = *(const uint4*)(Ag[pl] + abase + ks * 16 + ah * 4);
            dw[pl] = *(const uint4*)(Wg[pl] + wbase + ks * 16 + wo_);
        }
    };
    auto stS = [&](int buf, uint4 (&sa)[3], uint4 (&sw)[3]) {
#pragma unroll
        for (int pl = 0; pl < 3; pl++) {
            st4(&lA[buf][pl][aoff], sa[pl]);
            st4(&lW[buf][pl][woff], sw[pl]);
        }
    };
    auto mstep = [&](int buf) {
        short8b a0[2], a1[2], a2[2];
#pragma unroll
        for (int i = 0; i < 2; i++) {
            int ra = wn + i * 16 + rl;
            a0[i] = ldfrag(lA[buf][0], ra, kq);
            a1[i] = ldfrag(lA[buf][1], ra, kq);
            a2[i] = ldfrag(lA[buf][2], ra, kq);
        }
        short8b w0[2], w1[2], w2[2];
#pragma unroll
        for (int j = 0; j < 2; j++) {
            int rw = wm + j * 16 + rl;
            w0[j] = ldfrag(lW[buf][0], rw, kq);
            w1[j] = ldfrag(lW[buf][1], rw, kq);
            w2[j] = ldfrag(lW[buf][2], rw, kq);
        }
#pragma unroll
        for (int i = 0; i < 2; i++) {
#pragma unroll
            for (int j = 0; j < 2; j++) {
                MFMA6(acc[i][j], a0[i], a1[i], a2[i], w0[j], w1[j], w2[j]);
            }
        }
    };

    int nst = K >> 5;                  // 8/16/32 — all even
    loadS(0, aA, wA);
    stS(0, aA, wA);
    loadS(1, aB, wB);
    for (int idx = 0; idx < nst; idx += 2) {
        if (idx + 2 < nst) loadS(idx + 2, aA, wA);
        __syncthreads();
        mstep(0);
        stS(1, aB, wB);
        if (idx + 3 < nst) loadS(idx + 3, aB, wB);
        __syncthreads();
        mstep(1);
        if (idx + 2 < nst) stS(0, aA, wA);
    }

#pragma unroll
    for (int j = 0; j < 2; j++) {
        int mm = m0 + wm + j * 16 + rl;
        float bs = bias ? bias[mm] : 0.f;
        float gm = gma[mm], bt = bta[mm];
#pragma unroll
        for (int i = 0; i < 2; i++) {
            int tn = n0 + wn + i * 16 + kq * 4;
            f32x4 a = acc[i][j];
#pragma unroll
            for (int r = 0; r < 4; r++) {
                int gn2 = tn + r;
                if (gn2 >= N) continue;
                float v = (a[r] + bs) * gm + bt;
                if (do_gelu) v = gelu_f(v);
                size_t off = ((size_t)bz * N + gn2) * M + mm;
                if (R0) v += (bf2f(R0[off]) + bf2f(R1[off])) + bf2f(R2[off]);
                unsigned pm = pack2(v);
                C0[off] = (unsigned short)(pm >> 16);
                C1[off] = (unsigned short)(pm & 0xFFFFu);
                C2[off] = (unsigned short)bf16r(v - unpk(pm));
            }
        }
    }
}

// ---------------------------------------------------------------------------
// MFMA distance syrk, 6-term, upper-tri + mirror, 64x64, r11: dbuf LDS,
// one barrier per k-step. Numerics identical to r10.
// ---------------------------------------------------------------------------
__global__ __launch_bounds__(256, 2)
void mdist6p_k(const unsigned short* __restrict__ H0, const unsigned short* __restrict__ H1,
               const unsigned short* __restrict__ H2, const float* __restrict__ SQ,
               float* __restrict__ NEG, int Nn, int K, int bz)
{
    __shared__ __align__(16) unsigned lA[2][3][64 * 18];
    __shared__ __align__(16) unsigned lW[2][3][64 * 18];
    int q = blockIdx.x;
    int ti = 0;
    while (q >= 40 - ti) { q -= 40 - ti; ti++; }
    int tj = ti + q;
    int i0 = ti * 64, j0 = tj * 64;
    int tid = threadIdx.x, wave = tid >> 6, lane = tid & 63;
    int wn = (wave & 1) * 32, wm = (wave >> 1) * 32;
    int rl = lane & 15, kq = lane >> 4;

    f32x4 acc[2][2] = {};

    const unsigned* Hg[3] = {(const unsigned*)H0, (const unsigned*)H1, (const unsigned*)H2};

    int ar = tid >> 2, ah = tid & 3;
    int gi = i0 + ar; if (gi >= Nn) gi = Nn - 1;
    int gj = j0 + ar; if (gj >= Nn) gj = Nn - 1;
    size_t ibase = (((size_t)bz * Nn + gi) * K) >> 1;
    size_t jbase = (((size_t)bz * Nn + gj) * K) >> 1;
    int aoff = ar * 18 + ah * 4;

    uint4 iA[3], iB[3], jA[3], jB[3];

    auto loadS = [&](int ks, uint4 (&di)[3], uint4 (&dj)[3]) {
#pragma unroll
        for (int pl = 0; pl < 3; pl++) {
            di[pl] = *(const uint4*)(Hg[pl] + ibase + ks * 16 + ah * 4);
            dj[pl] = *(const uint4*)(Hg[pl] + jbase + ks * 16 + ah * 4);
        }
    };
    auto stS = [&](int buf, uint4 (&si)[3], uint4 (&sj)[3]) {
#pragma unroll
        for (int pl = 0; pl < 3; pl++) {
            st4(&lA[buf][pl][aoff], si[pl]);
            st4(&lW[buf][pl][aoff], sj[pl]);
        }
    };
    auto mstep = [&](int buf) {
        short8b a0[2], a1[2], a2[2], w0[2], w1[2], w2[2];
#pragma unroll
        for (int i = 0; i < 2; i++) {
            int ra = wn + i * 16 + rl;
            a0[i] = ldfrag(lA[buf][0], ra, kq);
            a1[i] = ldfrag(lA[buf][1], ra, kq);
            a2[i] = ldfrag(lA[buf][2], ra, kq);
            int rw = wm + i * 16 + rl;
            w0[i] = ldfrag(lW[buf][0], rw, kq);
            w1[i] = ldfrag(lW[buf][1], rw, kq);
            w2[i] = ldfrag(lW[buf][2], rw, kq);
        }
#pragma unroll
        for (int i = 0; i < 2; i++) {
#pragma unroll
            for (int j = 0; j < 2; j++) {
                MFMA6(acc[i][j], a0[i], a1[i], a2[i], w0[j], w1[j], w2[j]);
            }
        }
    };

    int nst = K >> 5;   // 8
    loadS(0, iA, jA);
    stS(0, iA, jA);
    loadS(1, iB, jB);
    for (int idx = 0; idx < nst; idx += 2) {
        if (idx + 2 < nst) loadS(idx + 2, iA, jA);
        __syncthreads();
        mstep(0);
        stS(1, iB, jB);
        if (idx + 3 < nst) loadS(idx + 3, iB, jB);
        __syncthreads();
        mstep(1);
        if (idx + 2 < nst) stS(0, iA, jA);
    }

    const float* SQb = SQ + (size_t)bz * Nn;
#pragma unroll
    for (int j = 0; j < 2; j++) {
        int nj = j0 + wm + j * 16 + rl;
        if (nj >= Nn) continue;
        float sj = SQb[nj];
#pragma unroll
        for (int i = 0; i < 2; i++) {
            int nio = i0 + wn + i * 16 + kq * 4;
            f32x4 a = acc[i][j];
#pragma unroll
            for (int r = 0; r < 4; r++) {
                int ni = nio + r;
                if (ni >= Nn) continue;
                float d = 2.f * a[r] - SQb[ni] - sj;
                NEG[(size_t)ni * Nn + nj] = d;
                if (i0 != j0) NEG[(size_t)nj * Nn + ni] = d;
            }
        }
    }
}

// ---------------------------------------------------------------------------
// MFMA implicit-im2col 3x3 conv (stem L3/L4), r11: BN=64 + dbuf LDS,
// one barrier per k-step. Numerics identical.
// ---------------------------------------------------------------------------
template <int CIN>
__global__ __launch_bounds__(256, 2)
void mconv6p_k(const unsigned short* __restrict__ T0, const unsigned short* __restrict__ T1,
               const unsigned short* __restrict__ T2,
               const unsigned short* __restrict__ Wc0, const unsigned short* __restrict__ Wc1,
               const unsigned short* __restrict__ Wc2,
               const float* __restrict__ bias, float* __restrict__ out,
               int Cout, int Hin, int Win, int Hout, int Wout, int stride)
{
    const int K = 9 * CIN;
    __shared__ __align__(16) unsigned lA[2][3][64 * 18];
    __shared__ __align__(16) unsigned lW[2][3][64 * 18];
    int bz = blockIdx.z;
    int n0 = blockIdx.x * 64, m0 = blockIdx.y * 64;
    int HWo = Hout * Wout;
    int tid = threadIdx.x, wave = tid >> 6, lane = tid & 63;
    int wn = (wave & 1) * 32, wm = (wave >> 1) * 32;
    int rl = lane & 15, kq = lane >> 4;

    f32x4 acc[2][2] = {};

    const unsigned* Tg[3] = {(const unsigned*)T0, (const unsigned*)T1, (const unsigned*)T2};
    const unsigned* Wg[3] = {(const unsigned*)Wc0, (const unsigned*)Wc1, (const unsigned*)Wc2};

    int ar = tid >> 2, ah = tid & 3;
    int s = n0 + ar; if (s >= HWo) s = HWo - 1;
    int ho = s / Wout, wo = s % Wout;
    int aoff = ar * 18 + ah * 4;

    int wr_ = tid >> 2, wo_ = (tid & 3) * 4;
    size_t wbase = ((size_t)(m0 + wr_) * K) >> 1;
    int woff = wr_ * 18 + wo_;
    size_t HWi = (size_t)Hin * Win;

    uint4 aA[3], aB[3], wA[3], wB[3];

    auto loadS = [&](int ks, uint4 (&da)[3], uint4 (&dw)[3]) {
        int kk = ks * 32;
        int tap = kk / CIN;
        int kh = tap / 3, kw = tap % 3;
        int hi = ho * stride - 1 + kh;
        int wi = wo * stride - 1 + kw;
        bool ok = (hi >= 0 && hi < Hin && wi >= 0 && wi < Win);
        if (ok) {
            size_t base = (((size_t)bz * HWi + (size_t)(hi * Win + wi)) * CIN + (kk % CIN)) >> 1;
#pragma unroll
            for (int pl = 0; pl < 3; pl++)
                da[pl] = *(const uint4*)(Tg[pl] + base + ah * 4);
        } else {
            uint4 z; z.x = 0; z.y = 0; z.z = 0; z.w = 0;
#pragma unroll
            for (int pl = 0; pl < 3; pl++) da[pl] = z;
        }
#pragma unroll
        for (int pl = 0; pl < 3; pl++)
            dw[pl] = *(const uint4*)(Wg[pl] + wbase + ks * 16 + wo_);
    };
    auto stS = [&](int buf, uint4 (&sa)[3], uint4 (&sw)[3]) {
#pragma unroll
        for (int pl = 0; pl < 3; pl++) {
            st4(&lA[buf][pl][aoff], sa[pl]);
            st4(&lW[buf][pl][woff], sw[pl]);
        }
    };
    auto mstep = [&](int buf) {
        short8b a0[2], a1[2], a2[2];
#pragma unroll
        for (int i = 0; i < 2; i++) {
            int ra = wn + i * 16 + rl;
            a0[i] = ldfrag(lA[buf][0], ra, kq);
            a1[i] = ldfrag(lA[buf][1], ra, kq);
            a2[i] = ldfrag(lA[buf][2], ra, kq);
        }
        short8b w0[2], w1[2], w2[2];
#pragma unroll
        for (int j = 0; j < 2; j++) {
            int rw = wm + j * 16 + rl;
            w0[j] = ldfrag(lW[buf][0], rw, kq);
            w1[j] = ldfrag(lW[buf][1], rw, kq);
            w2[j] = ldfrag(lW[buf][2], rw, kq);
        }
#pragma unroll
        for (int i = 0; i < 2; i++) {
#pragma unroll
            for (int j = 0; j < 2; j++) {
                MFMA6(acc[i][j], a0[i], a1[i], a2[i], w0[j], w1[j], w2[j]);
            }
        }
    };

    int nst = K >> 5;   // 36 (L3) / 72 (L4): even
    loadS(0, aA, wA);
    stS(0, aA, wA);
    loadS(1, aB, wB);
    for (int idx = 0; idx < nst; idx += 2) {
        if (idx + 2 < nst) loadS(idx + 2, aA, wA);
        __syncthreads();
        mstep(0);
        stS(1, aB, wB);
        if (idx + 3 < nst) loadS(idx + 3, aB, wB);
        __syncthreads();
        mstep(1);
        if (idx + 2 < nst) stS(0, aA, wA);
    }

#pragma unroll
    for (int j = 0; j < 2; j++) {
        int mm = m0 + wm + j * 16 + rl;
        float bs = bias[mm];
#pragma unroll
        for (int i = 0; i < 2; i++) {
            int tn = n0 + wn + i * 16 + kq * 4;
            f32x4 a = acc[i][j];
#pragma unroll
            for (int r = 0; r < 4; r++) {
                int gn2 = tn + r;
                if (gn2 < HWo)
                    out[((size_t)bz * Cout + mm) * HWo + gn2] = a[r] + bs;
            }
        }
    }
}

// ---------------------------------------------------------------------------
// posadd + transpose — unchanged
// ---------------------------------------------------------------------------
__global__ __launch_bounds__(256)
void posadd_k(const float* __restrict__ xin, unsigned short* __restrict__ X0,
              unsigned short* __restrict__ X1, unsigned short* __restrict__ X2)
{
    __shared__ float tile[64][65];
    int t0 = blockIdx.x * 64, c0 = blockIdx.y * 64, b = blockIdx.z;
    int tid = threadIdx.x;
    int tl = tid & 63;
    const float* inb = xin + (size_t)b * 256 * 2500;
#pragma unroll
    for (int p = 0; p < 16; p++) {
        int c = (tid >> 6) + p * 4;
        int t = t0 + tl;
        tile[c][tl] = (t < 2500) ? inb[(size_t)(c0 + c) * 2500 + t] : 0.f;
    }
    __syncthreads();
#pragma unroll
    for (int p = 0; p < 16; p++) {
        int tt = (tid >> 6) + p * 4;
        int t = t0 + tt;
        if (t >= 2500) continue;
        int ch = c0 + tl;
        int yy = t / 50, xx = t % 50;
        int cc = ch & 127;
        double v = (double)((ch < 128) ? (yy + 1) : (xx + 1));
        v = v * (6.283185307179586476925287 / 50.0);
        double e = (double)(2 * (cc >> 1)) / 128.0;
        double d = pow(10000.0, e);
        double a = v / d;
        double pp = (cc & 1) ? cos(a) : sin(a);
        float val = tile[tl][tt] + (float)pp;
        size_t off = ((size_t)b * 2500 + t) * 256 + ch;
        unsigned pm = pack2(val);
        X0[off] = (unsigned short)(pm >> 16);
        X1[off] = (unsigned short)(pm & 0xFFFFu);
        X2[off] = (unsigned short)bf16r(val - unpk(pm));
    }
}

// ---------------------------------------------------------------------------
// Per-token normalize (double accumulation) — unchanged
// ---------------------------------------------------------------------------
__global__ __launch_bounds__(256)
void tok_k(const unsigned short* __restrict__ H0, const unsigned short* __restrict__ H1,
           const unsigned short* __restrict__ H2, unsigned short* __restrict__ T0,
           unsigned short* __restrict__ T1, unsigned short* __restrict__ T2,
           float* __restrict__ SQ)
{
    int wave = threadIdx.x >> 6, lane = threadIdx.x & 63;
    int t = blockIdx.x * 4 + wave;
    int b = blockIdx.y;
    size_t base = ((size_t)b * 2500 + t) * 128;   // u32 pair index
    const unsigned* h0 = (const unsigned*)H0 + base;
    const unsigned* h1 = (const unsigned*)H1 + base;
    const unsigned* h2 = (const unsigned*)H2 + base;
    float v[4];
    double s = 0.0;
#pragma unroll
    for (int g = 0; g < 2; g++) {
        unsigned ua = h0[lane + g * 64], ub = h1[lane + g * 64], uc = h2[lane + g * 64];
        float lo = (__uint_as_float(ua << 16) + __uint_as_float(ub << 16)) + __uint_as_float(uc << 16);
        float hi = (__uint_as_float(ua & 0xFFFF0000u) + __uint_as_float(ub & 0xFFFF0000u)) + __uint_as_float(uc & 0xFFFF0000u);
        v[2 * g] = lo; v[2 * g + 1] = hi;
        s += (double)lo * lo + (double)hi * hi;
    }
#pragma unroll
    for (int off = 32; off > 0; off >>= 1) s += __shfl_xor(s, off);
    float r = (float)(1.0 / sqrt(s + 1e-12));
    unsigned* t0 = (unsigned*)T0 + base;
    unsigned* t1 = (unsigned*)T1 + base;
    unsigned* t2 = (unsigned*)T2 + base;
    double s2 = 0.0;
#pragma unroll
    for (int g = 0; g < 2; g++) {
        float x0 = v[2 * g] * r, x1 = v[2 * g + 1] * r;
        s2 += (double)x0 * x0 + (double)x1 * x1;
        unsigned p0 = pack2(x0), p1 = pack2(x1);
        t0[lane + g * 64] = (p0 >> 16) | (p1 & 0xFFFF0000u);
        t1[lane + g * 64] = (p0 & 0xFFFFu) | (p1 << 16);
        t2[lane + g * 64] = bf16r(x0 - unpk(p0)) | (bf16r(x1 - unpk(p1)) << 16);
    }
#pragma unroll
    for (int off = 32; off > 0; off >>= 1) s2 += __shfl_xor(s2, off);
    if (lane == 0) SQ[b * 2500 + t] = (float)s2;
}

// ---------------------------------------------------------------------------
// top-(k*dil): one wave per row — unchanged
// ---------------------------------------------------------------------------
DEVI unsigned long long pack_key(float x, unsigned idx)
{
    unsigned u = __float_as_uint(x);
    u = (u & 0x80000000u) ? ~u : (u | 0x80000000u);
    return ((unsigned long long)u << 32) | (unsigned long long)(0xFFFFFFFFu - idx);
}

__global__ __launch_bounds__(128)
void topk_k(const float* __restrict__ NEGc, int* __restrict__ IDX,
            int rows, int kd, int dil, int kout, int bz)
{
    __shared__ float vals[2][2560];
    int wave = threadIdx.x >> 6;
    int lane = threadIdx.x & 63;
    int i = blockIdx.x * 2 + wave;
    if (i >= rows) return;
    const float* row = NEGc + (size_t)i * 2500;
    float* v = vals[wave];
    for (int j = lane; j < 2560; j += 64)
        v[j] = (j < 2500) ? (row[j] + 0.0f) : -INFINITY;
    unsigned long long key = pack_key(-INFINITY, 0xFFFFFFFFu);
    for (int q = 0; q < 40; q++) {
        int pos = lane * 40 + q;
        unsigned long long k2 = pack_key(v[pos], (unsigned)pos);
        if (k2 > key) key = k2;
    }
    for (int t = 0; t < kd; t++) {
        unsigned long long r = key;
#pragma unroll
        for (int off = 32; off > 0; off >>= 1) {
            unsigned long long o = __shfl_xor(r, off);
            if (o > r) r = o;
        }
        int sel = (int)(0xFFFFFFFFu - (unsigned)(r & 0xFFFFFFFFull));
        if ((unsigned)sel >= 2500u) sel = 0;
        if (lane == 0 && t % dil == 0)
            IDX[(size_t)(bz * 2500 + i) * kout + t / dil] = sel;
        int lo = sel / 40;
        if (lane == lo) v[sel] = -INFINITY;
        int pos = lo * 40 + lane;
        float x = (lane < 40) ? v[pos] : -INFINITY;
        unsigned long long k2 = pack_key(x, (lane < 40) ? (unsigned)pos : 0xFFFFFFFFu);
#pragma unroll
        for (int off = 32; off > 0; off >>= 1) {
            unsigned long long o = __shfl_xor(k2, off);
            if (o > k2) k2 = o;
        }
        if (lane == lo) key = k2;
    }
}

// ---------------------------------------------------------------------------
// Gather neighbors — unchanged
// ---------------------------------------------------------------------------
__global__ __launch_bounds__(256)
void gather_k(const unsigned short* __restrict__ H0, const unsigned short* __restrict__ H1,
              const unsigned short* __restrict__ H2, const int* __restrict__ IDX,
              unsigned short* __restrict__ F0, unsigned short* __restrict__ F1,
              unsigned short* __restrict__ F2, int k)
{
    int t = blockIdx.x;
    int b = blockIdx.y;
    int q = threadIdx.x;
    __shared__ int idx[18];
    if (q < k) {
        int ii = IDX[((size_t)b * 2500 + t) * k + q];
        if ((unsigned)ii >= 2500u) ii = 0;
        idx[q] = ii;
    }
    __syncthreads();
    size_t base = (size_t)b * 2500 * 256;
    size_t co = base + (size_t)t * 256 + q;
    float center = (bf2f(H0[co]) + bf2f(H1[co])) + bf2f(H2[co]);
    float mx = -INFINITY;
    for (int kk = 0; kk < k; kk++) {
        size_t no = base + (size_t)idx[kk] * 256 + q;
        float v = (bf2f(H0[no]) + bf2f(H1[no])) + bf2f(H2[no]);
        mx = fmaxf(mx, v - center);
    }
    unsigned pc = pack2(center), pd = pack2(mx);
    size_t fo = (size_t)b * 2500 * 256 + (size_t)t * 256 + q;  // u32 pair index
    ((unsigned*)F0)[fo] = (pc >> 16) | (pd & 0xFFFF0000u);
    ((unsigned*)F1)[fo] = (pc & 0xFFFFu) | (pd << 16);
    ((unsigned*)F2)[fo] = bf16r(center - unpk(pc)) | (bf16r(mx - unpk(pd)) << 16);
}

// ---------------------------------------------------------------------------
// Final transpose — unchanged
// ---------------------------------------------------------------------------
__global__ __launch_bounds__(256)
void outt_k(const unsigned short* __restrict__ X0, const unsigned short* __restrict__ X1,
            const unsigned short* __restrict__ X2, float* __restrict__ out)
{
    __shared__ float tile[64][65];
    int t0 = blockIdx.x * 64, c0 = blockIdx.y * 64, b = blockIdx.z;
    int tid = threadIdx.x;
    int tl = tid & 63;
#pragma unroll
    for (int p = 0; p < 16; p++) {
        int tt = (tid >> 6) + p * 4;
        int t = t0 + tt;
        int tc = (t < 2500) ? t : 2499;
        size_t off = ((size_t)b * 2500 + tc) * 256 + c0 + tl;
        tile[tl][tt] = (bf2f(X0[off]) + bf2f(X1[off])) + bf2f(X2[off]);
    }
    __syncthreads();
#pragma unroll
    for (int p = 0; p < 16; p++) {
        int cc = (tid >> 6) + p * 4;
        int t = t0 + tl;
        if (t < 2500)
            out[((size_t)b * 256 + c0 + cc) * 2500 + t] = tile[cc][tl];
    }
}

// ---------------------------------------------------------------------------
extern "C" void kernel_launch(void* const* d_in, const int* in_sizes, int n_in,
                              void* d_out, int out_size, void* d_ws, size_t ws_size,
                              hipStream_t stream)
{
    (void)in_sizes; (void)n_in; (void)out_size; (void)ws_size;
    const float* x_in = (const float*)d_in[0];
    const float *swp[5], *sbp[5], *sgp[5], *sbep[5];
    for (int i = 0; i < 5; i++) {
        swp[i] = (const float*)d_in[1 + 4 * i];
        sbp[i] = (const float*)d_in[2 + 4 * i];
        sgp[i] = (const float*)d_in[3 + 4 * i];
        sbep[i] = (const float*)d_in[4 + 4 * i];
    }
    const float* fc1_w = (const float*)d_in[21];
    const float* fc1_b = (const float*)d_in[22];
    const float* fc1_g = (const float*)d_in[23];
    const float* fc1_be = (const float*)d_in[24];
    const float* mr_w = (const float*)d_in[25];
    const float* mr_g = (const float*)d_in[26];
    const float* mr_be = (const float*)d_in[27];
    const float* fc2_w = (const float*)d_in[28];
    const float* fc2_b = (const float*)d_in[29];
    const float* fc2_g = (const float*)d_in[30];
    const float* fc2_be = (const float*)d_in[31];
    const float* ffn1_w = (const float*)d_in[32];
    const float* ffn1_b = (const float*)d_in[33];
    const float* ffn1_g = (const float*)d_in[34];
    const float* ffn1_be = (const float*)d_in[35];
    const float* ffn2_w = (const float*)d_in[36];
    const float* ffn2_b = (const float*)d_in[37];
    const float* ffn2_g = (const float*)d_in[38];
    const float* ffn2_be = (const float*)d_in[39];

    float* ws = (float*)d_ws;
    // ---- workspace layout (float units; r6-proven) ----
    const size_t NEG_F = 1920000;
    const size_t G_F   = 3840000;
    const size_t TI_F  = 3000000;      // stem-only, dead by main loop
    const size_t CW_F  = 10300000;
    const size_t X_F   = 12500000;
    const size_t HF_F  = 14420000;
    const size_t W_F   = 16340000;
    const size_t SQ_F  = 17815000;
    const size_t PART_F = 17820000;
    const size_t FIN_F = 17829000;
    const size_t IDX_F = 17830000;

    float* ping = ws;
    float* pong = ws + X_F;
    float* NEG  = ws + NEG_F;
    unsigned short* HT0 = (unsigned short*)ws;            // HTn planes
    unsigned short* HT1 = HT0 + 1280000;
    unsigned short* HT2 = HT0 + 2560000;
    unsigned short* Fp0 = (unsigned short*)ws;            // F planes
    unsigned short* Fp1 = Fp0 + 2560000;
    unsigned short* Fp2 = Fp0 + 5120000;
    unsigned short* Gp0 = (unsigned short*)(ws + G_F);    // G planes
    unsigned short* Gp1 = Gp0 + 2560000;
    unsigned short* Gp2 = Gp0 + 5120000;
    unsigned short* H20 = (unsigned short*)ws;            // HF2 planes
    unsigned short* H21 = H20 + 5120000;
    unsigned short* H22 = H20 + 10240000;
    unsigned short* TI0 = (unsigned short*)(ws + TI_F);   // stem split-T planes
    unsigned short* CW0 = (unsigned short*)(ws + CW_F);
    unsigned short* X0 = (unsigned short*)(ws + X_F);
    unsigned short* X1 = X0 + 1280000;
    unsigned short* X2 = X0 + 2560000;
    unsigned short* HF0 = (unsigned short*)(ws + HF_F);
    unsigned short* HF1 = HF0 + 1280000;
    unsigned short* HF2b = HF0 + 2560000;
    unsigned short* W0 = (unsigned short*)(ws + W_F);
    unsigned short* W1 = W0 + 983040;
    unsigned short* W2 = W0 + 1966080;
    float* SQ = ws + SQ_F;
    double* PART = (double*)(ws + PART_F);
    float* FIN = ws + FIN_F;
    int* IDX = (int*)(ws + IDX_F);

    // ---------------- stem ----------------
    int Co[5] = {32, 64, 128, 256, 256};
    int Ho[5] = {400, 200, 100, 50, 50};
    int Ssub[5] = {8, 8, 4, 2, 2};
    float* cur = nullptr;
    for (int l = 0; l < 5; l++) {
        float* outb = (l % 2 == 0) ? ping : pong;
        int HWo = Ho[l] * Ho[l];
        switch (l) {
        case 0:
            conv3x3_t<3, 32><<<dim3(625, 1, 2), 256, 0, stream>>>(
                x_in, swp[0], sbp[0], outb, 32, 800, 800, 400, 400, 2);
            break;
        case 1:
            conv3x3_t<32, 32><<<dim3(157, 2, 2), 256, 0, stream>>>(
                cur, swp[1], sbp[1], outb, 64, 400, 400, 200, 200, 2);
            break;
        case 2:
            conv3x3_t<64, 16><<<dim3(40, 8, 2), 256, 0, stream>>>(
                cur, swp[2], sbp[2], outb, 128, 200, 200, 100, 100, 2);
            break;
        case 3: {
            int psz = 2 * 10000 * 128;
            splitT_k<<<dim3(157, 2, 2), 256, 0, stream>>>(
                cur, TI0, TI0 + psz, TI0 + 2 * psz, 128, 10000);
            int tot = 256 * 1152;
            wconvp_k<<<(tot + 255) / 256, 256, 0, stream>>>(
                swp[3], CW0, CW0 + tot, CW0 + 2 * tot, 128, tot);
            mconv6p_k<128><<<dim3(40, 4, 2), 256, 0, stream>>>(
                TI0, TI0 + psz, TI0 + 2 * psz, CW0, CW0 + tot, CW0 + 2 * tot,
                sbp[3], outb, 256, 100, 100, 50, 50, 2);
            break;
        }
        case 4: {
            int psz = 2 * 2500 * 256;
            splitT_k<<<dim3(40, 4, 2), 256, 0, stream>>>(
                cur, TI0, TI0 + psz, TI0 + 2 * psz, 256, 2500);
            int tot = 256 * 2304;
            wconvp_k<<<(tot + 255) / 256, 256, 0, stream>>>(
                swp[4], CW0, CW0 + tot, CW0 + 2 * tot, 256, tot);
            mconv6p_k<256><<<dim3(40, 4, 2), 256, 0, stream>>>(
                TI0, TI0 + psz, TI0 + 2 * psz, CW0, CW0 + tot, CW0 + 2 * tot,
                sbp[4], outb, 256, 50, 50, 50, 50, 1);
            break;
        }
        }
        int cpg = Co[l] / 32;
        gn_stats_k<<<dim3(Ssub[l], 32, 2), 256, 0, stream>>>(outb, PART, Co[l], HWo, cpg, Ssub[l]);
        gn_reduce_k<<<1, 64, 0, stream>>>(PART, FIN, Ssub[l], (double)cpg * (double)HWo);
        int total = 2 * Co[l] * HWo;
        gn_apply_k<<<(total + 255) / 256, 256, 0, stream>>>(outb, FIN, sgp[l], sbep[l],
                                                            Co[l], HWo, cpg, (l < 4) ? 1 : 0, total);
        cur = outb;
    }
    posadd_k<<<dim3(40, 4, 2), 256, 0, stream>>>(cur, X0, X1, X2);

    // ---------------- 12 Grapher + FFN blocks ----------------
    const int KS[12] = {9, 9, 10, 11, 12, 13, 13, 14, 15, 16, 17, 18};
    const int DILS[12] = {1, 1, 1, 1, 2, 2, 2, 2, 3, 3, 3, 3};
    const int D = 256, N = 2500;

    for (int i = 0; i < 12; i++) {
        pack5p_k<<<3840, 256, 0, stream>>>(
            fc1_w + (size_t)i * 65536, mr_w + (size_t)i * 262144,
            fc2_w + (size_t)i * 131072, ffn1_w + (size_t)i * 262144,
            ffn2_w + (size_t)i * 262144, W0, W1, W2);

        // fc1 -> HF planes
        mgemm6p_k<<<dim3(40, 4, 2), 256, 0, stream>>>(
            X0, X1, X2, W0, W1, W2,
            fc1_b + i * D, fc1_g + i * D, fc1_be + i * D,
            nullptr, nullptr, nullptr, HF0, HF1, HF2b, N, D, D, 0);
        tok_k<<<dim3(625, 2), 256, 0, stream>>>(HF0, HF1, HF2b, HT0, HT1, HT2, SQ);
        for (int bz = 0; bz < 2; bz++) {
            mdist6p_k<<<dim3(820, 1, 1), 256, 0, stream>>>(HT0, HT1, HT2, SQ, NEG, N, D, bz);
            topk_k<<<dim3(1250, 1, 1), 128, 0, stream>>>(NEG, IDX, N,
                                                         KS[i] * DILS[i], DILS[i], KS[i], bz);
        }
        gather_k<<<dim3(2500, 2), 256, 0, stream>>>(HF0, HF1, HF2b, IDX, Fp0, Fp1, Fp2, KS[i]);
        // mr -> G planes
        mgemm6p_k<<<dim3(40, 8, 2), 256, 0, stream>>>(
            Fp0, Fp1, Fp2, W0 + 65536, W1 + 65536, W2 + 65536,
            nullptr, mr_g + i * 512, mr_be + i * 512,
            nullptr, nullptr, nullptr, Gp0, Gp1, Gp2, N, 512, 512, 1);
        // fc2 + residual -> X planes
        mgemm6p_k<<<dim3(40, 4, 2), 256, 0, stream>>>(
            Gp0, Gp1, Gp2, W0 + 327680, W1 + 327680, W2 + 327680,
            fc2_b + i * D, fc2_g + i * D, fc2_be + i * D,
            X0, X1, X2, X0, X1, X2, N, D, 512, 0);
        // ffn1 -> HF2 planes
        mgemm6p_k<<<dim3(40, 16, 2), 256, 0, stream>>>(
            X0, X1, X2, W0 + 458752, W1 + 458752, W2 + 458752,
            ffn1_b + i * 1024, ffn1_g + i * 1024, ffn1_be + i * 1024,
            nullptr, nullptr, nullptr, H20, H21, H22, N, 1024, D, 1);
        // ffn2 + residual -> X planes
        mgemm6p_k<<<dim3(40, 4, 2), 256, 0, stream>>>(
            H20, H21, H22, W0 + 720896, W1 + 720896, W2 + 720896,
            ffn2_b + i * D, ffn2_g + i * D, ffn2_be + i * D,
            X0, X1, X2, X0, X1, X2, N, D, 1024, 0);
    }

    outt_k<<<dim3(40, 4, 2), 256, 0, stream>>>(X0, X1, X2, (float*)d_out);
}

// Round 12
// 4547.229 us; speedup vs baseline: 1.0141x; 1.0141x over previous
//
#include <hip/hip_runtime.h>
#include <math.h>

#define DEVI static __device__ __forceinline__

typedef __attribute__((ext_vector_type(8))) short short8b;  // 8 bf16 (4 VGPR)
typedef __attribute__((ext_vector_type(4))) float f32x4;

DEVI float gelu_f(float x) { return 0.5f * x * (1.0f + erff(x * 0.70710678118654752440f)); }

// ---- 3-split bf16: x ~= b0 + b1 + b2 (each RN bf16); storage = 3 planes ----
DEVI unsigned pack2(float x)
{
    unsigned xb = __float_as_uint(x);
    unsigned hi = (xb + 0x7FFFu + ((xb >> 16) & 1u)) & 0xFFFF0000u;
    float lof = x - __uint_as_float(hi);
    unsigned lb = __float_as_uint(lof);
    unsigned lo = (lb + 0x7FFFu + ((lb >> 16) & 1u)) >> 16;
    return hi | lo;
}
DEVI float unpk(unsigned u)
{
    return __uint_as_float(u & 0xFFFF0000u) + __uint_as_float(u << 16);
}
DEVI unsigned bf16r(float x)
{
    unsigned b = __float_as_uint(x);
    return (b + 0x7FFFu + ((b >> 16) & 1u)) >> 16;
}
DEVI float bf2f(unsigned short u) { return __uint_as_float((unsigned)u << 16); }

// LDS plane row: 32 bf16 = 16 data u32 + 2 pad = 18 u32 stride (proven r4).
DEVI short8b ldfrag(const unsigned* P, int row, int kq)
{
    const unsigned* b = P + row * 18 + kq * 2;
    union { uint2 h[2]; short8b s; } r;
    r.h[0] = *(const uint2*)(b);
    r.h[1] = *(const uint2*)(b + 8);
    return r.s;
}
DEVI void st8(unsigned* b, uint4 v0, uint4 v1)
{
    uint2 t;
    t.x = v0.x; t.y = v0.y; *(uint2*)(b) = t;
    t.x = v0.z; t.y = v0.w; *(uint2*)(b + 2) = t;
    t.x = v1.x; t.y = v1.y; *(uint2*)(b + 4) = t;
    t.x = v1.z; t.y = v1.w; *(uint2*)(b + 6) = t;
}
DEVI void st4(unsigned* b, uint4 v0)
{
    uint2 t;
    t.x = v0.x; t.y = v0.y; *(uint2*)(b) = t;
    t.x = v0.z; t.y = v0.w; *(uint2*)(b + 2) = t;
}

#define MFMA6(ACC, A0, A1, A2F, W0, W1, W2F) do { \
    ACC = __builtin_amdgcn_mfma_f32_16x16x32_bf16(A2F, W0, ACC, 0, 0, 0); \
    ACC = __builtin_amdgcn_mfma_f32_16x16x32_bf16(A0, W2F, ACC, 0, 0, 0); \
    ACC = __builtin_amdgcn_mfma_f32_16x16x32_bf16(A1, W1, ACC, 0, 0, 0); \
    ACC = __builtin_amdgcn_mfma_f32_16x16x32_bf16(A1, W0, ACC, 0, 0, 0); \
    ACC = __builtin_amdgcn_mfma_f32_16x16x32_bf16(A0, W1, ACC, 0, 0, 0); \
    ACC = __builtin_amdgcn_mfma_f32_16x16x32_bf16(A0, W0, ACC, 0, 0, 0); \
} while (0)

// ---------------------------------------------------------------------------
// Direct 3x3 conv for small Cin (stem L0-L2). r12: grid axes SWAPPED so the
// co-groups sharing a site-chunk are dispatch-adjacent (L2 input reuse):
// blockIdx.x = co-group (small), blockIdx.y = site chunk.
// ---------------------------------------------------------------------------
template <int CIN, int NCO>
__global__ __launch_bounds__(256)
void conv3x3_t(const float* __restrict__ in, const float* __restrict__ w,
               const float* __restrict__ bias, float* __restrict__ out,
               int Cout, int Hin, int Win, int Hout, int Wout, int stride)
{
    __shared__ __align__(16) float wlds[CIN * 9 * NCO];
    int b = blockIdx.z;
    int co0 = blockIdx.x * NCO;
    int tid = threadIdx.x;
    int HWo = Hout * Wout;
    int s = blockIdx.y * 256 + tid;
    int sc = (s < HWo) ? s : (HWo - 1);
    int ho = sc / Wout, wo = sc % Wout;
    float acc[NCO];
#pragma unroll
    for (int j = 0; j < NCO; j++) acc[j] = bias[co0 + j];
    const float* inb = in + (size_t)b * CIN * Hin * Win;
    size_t HWi = (size_t)Hin * Win;

    const int nw = NCO * CIN * 9;
    for (int i = tid; i < nw; i += 256) {
        int j = i % NCO;
        int rest = i / NCO;
        int ci = rest % CIN, tap = rest / CIN;
        wlds[i] = w[((size_t)(co0 + j) * CIN + ci) * 9 + tap];
    }
    __syncthreads();
    for (int kh = 0; kh < 3; kh++) {
        int hi = ho * stride - 1 + kh;
        bool okh = (hi >= 0 && hi < Hin);
        for (int kw = 0; kw < 3; kw++) {
            int wi = wo * stride - 1 + kw;
            if (!okh || wi < 0 || wi >= Win) continue;
            int tap = kh * 3 + kw;
            const float* ip = inb + (size_t)hi * Win + wi;
            const float* wp = wlds + (size_t)tap * CIN * NCO;
#pragma unroll 4
            for (int ci = 0; ci < CIN; ci++) {
                float xv = ip[(size_t)ci * HWi];
                const float* wq = wp + ci * NCO;
#pragma unroll
                for (int j4 = 0; j4 < NCO; j4 += 4) {
                    float4 wv = *(const float4*)(wq + j4);
                    acc[j4 + 0] += xv * wv.x; acc[j4 + 1] += xv * wv.y;
                    acc[j4 + 2] += xv * wv.z; acc[j4 + 3] += xv * wv.w;
                }
            }
        }
    }
    if (s < HWo) {
        size_t ob = ((size_t)b * Cout + co0) * HWo + s;
#pragma unroll
        for (int j = 0; j < NCO; j++) out[ob + (size_t)j * HWo] = acc[j];
    }
}

// ---------------------------------------------------------------------------
// GroupNorm (deterministic) — unchanged
// ---------------------------------------------------------------------------
__global__ __launch_bounds__(256)
void gn_stats_k(const float* __restrict__ x, double* __restrict__ part,
                int C, int HW, int cpg, int S)
{
    int srt = blockIdx.x, g = blockIdx.y, b = blockIdx.z;
    long len = (long)cpg * HW;
    long chunk = (len + S - 1) / S;
    long lo = (long)srt * chunk;
    long hi = lo + chunk; if (hi > len) hi = len;
    const float* xp = x + ((size_t)b * C + (size_t)g * cpg) * HW;
    double s1 = 0.0, s2 = 0.0;
    for (long i = lo + threadIdx.x; i < hi; i += 256) {
        double v = (double)xp[i];
        s1 += v; s2 += v * v;
    }
    __shared__ double r1[256], r2[256];
    r1[threadIdx.x] = s1; r2[threadIdx.x] = s2;
    __syncthreads();
    for (int t = 128; t > 0; t >>= 1) {
        if (threadIdx.x < t) { r1[threadIdx.x] += r1[threadIdx.x + t]; r2[threadIdx.x] += r2[threadIdx.x + t]; }
        __syncthreads();
    }
    if (threadIdx.x == 0) {
        size_t slot = ((size_t)(b * 32 + g) * S + srt) * 2;
        part[slot] = r1[0];
        part[slot + 1] = r2[0];
    }
}

__global__ __launch_bounds__(64)
void gn_reduce_k(const double* __restrict__ part, float* __restrict__ fin,
                 int S, double cnt)
{
    int t = threadIdx.x;
    double s1 = 0.0, s2 = 0.0;
    for (int s = 0; s < S; s++) {
        size_t slot = ((size_t)t * S + s) * 2;
        s1 += part[slot];
        s2 += part[slot + 1];
    }
    double m = s1 / cnt;
    double var = s2 / cnt - m * m;
    double inv = 1.0 / sqrt(var + 1e-5);
    fin[t * 2] = (float)m;
    fin[t * 2 + 1] = (float)inv;
}

__global__ __launch_bounds__(256)
void gn_apply_k(float* __restrict__ x, const float* __restrict__ fin,
                const float* __restrict__ gma, const float* __restrict__ bta,
                int C, int HW, int cpg, int do_gelu, int total)
{
    int idx = blockIdx.x * 256 + threadIdx.x;
    if (idx >= total) return;
    int c = (idx / HW) % C;
    int b = idx / (HW * C);
    int g = c / cpg;
    float m = fin[(b * 32 + g) * 2];
    float inv = fin[(b * 32 + g) * 2 + 1];
    float v = (x[idx] - m) * inv * gma[c] + bta[c];
    if (do_gelu) v = gelu_f(v);
    x[idx] = v;
}

// ---------------------------------------------------------------------------
// Transpose+split stem input: in[b][c][hw] fp32 -> 3 planes [b][hw][c] bf16
// ---------------------------------------------------------------------------
__global__ __launch_bounds__(256)
void splitT_k(const float* __restrict__ in, unsigned short* __restrict__ P0,
              unsigned short* __restrict__ P1, unsigned short* __restrict__ P2,
              int C, int HW)
{
    __shared__ float tile[64][65];
    int h0 = blockIdx.x * 64, c0 = blockIdx.y * 64, b = blockIdx.z;
    int tid = threadIdx.x;
    int tl = tid & 63;
    const float* inb = in + (size_t)b * C * HW;
#pragma unroll
    for (int p = 0; p < 16; p++) {
        int c = (tid >> 6) + p * 4;
        int h = h0 + tl;
        tile[c][tl] = (h < HW) ? inb[(size_t)(c0 + c) * HW + h] : 0.f;
    }
    __syncthreads();
#pragma unroll
    for (int p = 0; p < 16; p++) {
        int hh = (tid >> 6) + p * 4;
        int h = h0 + hh;
        if (h >= HW) continue;
        int ch = c0 + tl;
        float v = tile[tl][hh];
        unsigned pm = pack2(v);
        size_t off = ((size_t)b * HW + h) * C + ch;
        P0[off] = (unsigned short)(pm >> 16);
        P1[off] = (unsigned short)(pm & 0xFFFFu);
        P2[off] = (unsigned short)bf16r(v - unpk(pm));
    }
}

// ---------------------------------------------------------------------------
// Conv weight pack to 3 planes, k = tap*Cin + ci — unchanged
// ---------------------------------------------------------------------------
__global__ __launch_bounds__(256)
void wconvp_k(const float* __restrict__ w, unsigned short* __restrict__ P0,
              unsigned short* __restrict__ P1, unsigned short* __restrict__ P2,
              int Cin, int total)
{
    int idx = blockIdx.x * 256 + threadIdx.x;
    if (idx >= total) return;
    int K = Cin * 9;
    int co = idx / K, k = idx % K;
    int tap = k / Cin, ci = k - tap * Cin;
    float v = w[((size_t)co * Cin + ci) * 9 + tap];
    unsigned pm = pack2(v);
    P0[idx] = (unsigned short)(pm >> 16);
    P1[idx] = (unsigned short)(pm & 0xFFFFu);
    P2[idx] = (unsigned short)bf16r(v - unpk(pm));
}

// ---------------------------------------------------------------------------
// Main-loop weight pack (fc1|mr|fc2|ffn1|ffn2) to 3 planes — unchanged
// ---------------------------------------------------------------------------
__global__ __launch_bounds__(256)
void pack5p_k(const float* __restrict__ s0, const float* __restrict__ s1,
              const float* __restrict__ s2, const float* __restrict__ s3,
              const float* __restrict__ s4, unsigned short* __restrict__ P0,
              unsigned short* __restrict__ P1, unsigned short* __restrict__ P2)
{
    int idx = blockIdx.x * 256 + threadIdx.x;   // grid exact: 983040
    float v;
    if (idx < 65536)       v = s0[idx];
    else if (idx < 327680) v = s1[idx - 65536];
    else if (idx < 458752) v = s2[idx - 327680];
    else if (idx < 720896) v = s3[idx - 458752];
    else                   v = s4[idx - 720896];
    unsigned pm = pack2(v);
    P0[idx] = (unsigned short)(pm >> 16);
    P1[idx] = (unsigned short)(pm & 0xFFFFu);
    P2[idx] = (unsigned short)bf16r(v - unpk(pm));
}

// ---------------------------------------------------------------------------
// MFMA GEMM, 6-term, plane storage, r10-proven: BN=64, single LDS buffer,
// issue-early register prefetch, occ-3.
// ---------------------------------------------------------------------------
template <int JT>
__global__ __launch_bounds__(256, 3)
void mgemm6p_k(const unsigned short* __restrict__ A0, const unsigned short* __restrict__ A1,
               const unsigned short* __restrict__ A2,
               const unsigned short* __restrict__ W0, const unsigned short* __restrict__ W1,
               const unsigned short* __restrict__ W2,
               const float* __restrict__ bias, const float* __restrict__ gma,
               const float* __restrict__ bta,
               const unsigned short* __restrict__ R0, const unsigned short* __restrict__ R1,
               const unsigned short* __restrict__ R2,
               unsigned short* __restrict__ C0, unsigned short* __restrict__ C1,
               unsigned short* __restrict__ C2,
               int N, int M, int K, int do_gelu)
{
    const int BM = 32 * JT;
    __shared__ __align__(16) unsigned lA[3][64 * 18];
    __shared__ __align__(16) unsigned lW[3][BM * 18];
    int bz = blockIdx.z;
    int n0 = blockIdx.x * 64, m0 = blockIdx.y * BM;
    int tid = threadIdx.x, wave = tid >> 6, lane = tid & 63;
    int wn = (wave & 1) * 32, wm = (wave >> 1) * (16 * JT);
    int rl = lane & 15, kq = lane >> 4;

    f32x4 acc[2][JT] = {};

    const unsigned* Ag[3] = {(const unsigned*)A0, (const unsigned*)A1, (const unsigned*)A2};
    const unsigned* Wg[3] = {(const unsigned*)W0, (const unsigned*)W1, (const unsigned*)W2};

    int ar = tid >> 2, ah = tid & 3;
    int aga = n0 + ar; if (aga >= N) aga = N - 1;
    size_t abase = (((size_t)bz * N + aga) * K) >> 1;
    unsigned* sA[3];
#pragma unroll
    for (int pl = 0; pl < 3; pl++) sA[pl] = &lA[pl][ar * 18 + ah * 4];

    int wr_ = (JT == 4) ? (tid >> 1) : (tid >> 2);
    int wo_ = (JT == 4) ? ((tid & 1) * 8) : ((tid & 3) * 4);
    size_t wbase = ((size_t)(m0 + wr_) * K) >> 1;
    unsigned* sW[3];
#pragma unroll
    for (int pl = 0; pl < 3; pl++) sW[pl] = &lW[pl][wr_ * 18 + wo_];

    uint4 pa[3], pw[3][2];

#pragma unroll
    for (int pl = 0; pl < 3; pl++) {
        pa[pl] = *(const uint4*)(Ag[pl] + abase + ah * 4);
        const unsigned* h = Wg[pl] + wbase + wo_;
        pw[pl][0] = *(const uint4*)(h);
        if (JT == 4) pw[pl][1] = *(const uint4*)(h + 4);
    }
#pragma unroll
    for (int pl = 0; pl < 3; pl++) {
        st4(sA[pl], pa[pl]);
        if (JT == 4) st8(sW[pl], pw[pl][0], pw[pl][1]); else st4(sW[pl], pw[pl][0]);
    }
    __syncthreads();

    for (int k0 = 0; k0 < K; k0 += 32) {
        bool more = (k0 + 32) < K;
        if (more) {
#pragma unroll
            for (int pl = 0; pl < 3; pl++) {
                pa[pl] = *(const uint4*)(Ag[pl] + abase + ((k0 + 32) >> 1) + ah * 4);
                const unsigned* h = Wg[pl] + wbase + ((k0 + 32) >> 1) + wo_;
                pw[pl][0] = *(const uint4*)(h);
                if (JT == 4) pw[pl][1] = *(const uint4*)(h + 4);
            }
        }
        short8b a0[2], a1[2], a2[2];
#pragma unroll
        for (int i = 0; i < 2; i++) {
            int ra = wn + i * 16 + rl;
            a0[i] = ldfrag(lA[0], ra, kq);
            a1[i] = ldfrag(lA[1], ra, kq);
            a2[i] = ldfrag(lA[2], ra, kq);
        }
        short8b w0[JT], w1[JT], w2[JT];
#pragma unroll
        for (int j = 0; j < JT; j++) {
            int rw = wm + j * 16 + rl;
            w0[j] = ldfrag(lW[0], rw, kq);
            w1[j] = ldfrag(lW[1], rw, kq);
            w2[j] = ldfrag(lW[2], rw, kq);
        }
#pragma unroll
        for (int i = 0; i < 2; i++) {
#pragma unroll
            for (int j = 0; j < JT; j++) {
                MFMA6(acc[i][j], a0[i], a1[i], a2[i], w0[j], w1[j], w2[j]);
            }
        }
        __syncthreads();
        if (more) {
#pragma unroll
            for (int pl = 0; pl < 3; pl++) {
                st4(sA[pl], pa[pl]);
                if (JT == 4) st8(sW[pl], pw[pl][0], pw[pl][1]); else st4(sW[pl], pw[pl][0]);
            }
            __syncthreads();
        }
    }

#pragma unroll
    for (int j = 0; j < JT; j++) {
        int mm = m0 + wm + j * 16 + rl;
        float bs = bias ? bias[mm] : 0.f;
        float gm = gma[mm], bt = bta[mm];
#pragma unroll
        for (int i = 0; i < 2; i++) {
            int tn = n0 + wn + i * 16 + kq * 4;
            f32x4 a = acc[i][j];
#pragma unroll
            for (int r = 0; r < 4; r++) {
                int gn2 = tn + r;
                if (gn2 >= N) continue;
                float v = (a[r] + bs) * gm + bt;
                if (do_gelu) v = gelu_f(v);
                size_t off = ((size_t)bz * N + gn2) * M + mm;
                if (R0) v += (bf2f(R0[off]) + bf2f(R1[off])) + bf2f(R2[off]);
                unsigned pm = pack2(v);
                C0[off] = (unsigned short)(pm >> 16);
                C1[off] = (unsigned short)(pm & 0xFFFFu);
                C2[off] = (unsigned short)bf16r(v - unpk(pm));
            }
        }
    }
}

// ---------------------------------------------------------------------------
// MFMA distance syrk, 6-term, upper-tri + mirror, r10-proven 64x64 occ-3.
// ---------------------------------------------------------------------------
__global__ __launch_bounds__(256, 3)
void mdist6p_k(const unsigned short* __restrict__ H0, const unsigned short* __restrict__ H1,
               const unsigned short* __restrict__ H2, const float* __restrict__ SQ,
               float* __restrict__ NEG, int Nn, int K, int bz)
{
    __shared__ __align__(16) unsigned lA[3][64 * 18];
    __shared__ __align__(16) unsigned lW[3][64 * 18];
    int q = blockIdx.x;
    int ti = 0;
    while (q >= 40 - ti) { q -= 40 - ti; ti++; }
    int tj = ti + q;
    int i0 = ti * 64, j0 = tj * 64;
    int tid = threadIdx.x, wave = tid >> 6, lane = tid & 63;
    int wn = (wave & 1) * 32, wm = (wave >> 1) * 32;
    int rl = lane & 15, kq = lane >> 4;

    f32x4 acc[2][2] = {};

    const unsigned* Hg[3] = {(const unsigned*)H0, (const unsigned*)H1, (const unsigned*)H2};

    int ar = tid >> 2, ah = tid & 3;
    int gi = i0 + ar; if (gi >= Nn) gi = Nn - 1;
    int gj = j0 + ar; if (gj >= Nn) gj = Nn - 1;
    size_t ibase = (((size_t)bz * Nn + gi) * K) >> 1;
    size_t jbase = (((size_t)bz * Nn + gj) * K) >> 1;
    unsigned* sA[3];
    unsigned* sW[3];
#pragma unroll
    for (int pl = 0; pl < 3; pl++) {
        sA[pl] = &lA[pl][ar * 18 + ah * 4];
        sW[pl] = &lW[pl][ar * 18 + ah * 4];
    }

    uint4 pa[3], pj[3];
#pragma unroll
    for (int pl = 0; pl < 3; pl++) {
        pa[pl] = *(const uint4*)(Hg[pl] + ibase + ah * 4);
        pj[pl] = *(const uint4*)(Hg[pl] + jbase + ah * 4);
    }
#pragma unroll
    for (int pl = 0; pl < 3; pl++) {
        st4(sA[pl], pa[pl]);
        st4(sW[pl], pj[pl]);
    }
    __syncthreads();

    for (int k0 = 0; k0 < K; k0 += 32) {
        bool more = (k0 + 32) < K;
        if (more) {
#pragma unroll
            for (int pl = 0; pl < 3; pl++) {
                pa[pl] = *(const uint4*)(Hg[pl] + ibase + ((k0 + 32) >> 1) + ah * 4);
                pj[pl] = *(const uint4*)(Hg[pl] + jbase + ((k0 + 32) >> 1) + ah * 4);
            }
        }
        short8b a0[2], a1[2], a2[2], w0[2], w1[2], w2[2];
#pragma unroll
        for (int i = 0; i < 2; i++) {
            int ra = wn + i * 16 + rl;
            a0[i] = ldfrag(lA[0], ra, kq);
            a1[i] = ldfrag(lA[1], ra, kq);
            a2[i] = ldfrag(lA[2], ra, kq);
            int rw = wm + i * 16 + rl;
            w0[i] = ldfrag(lW[0], rw, kq);
            w1[i] = ldfrag(lW[1], rw, kq);
            w2[i] = ldfrag(lW[2], rw, kq);
        }
#pragma unroll
        for (int i = 0; i < 2; i++) {
#pragma unroll
            for (int j = 0; j < 2; j++) {
                MFMA6(acc[i][j], a0[i], a1[i], a2[i], w0[j], w1[j], w2[j]);
            }
        }
        __syncthreads();
        if (more) {
#pragma unroll
            for (int pl = 0; pl < 3; pl++) {
                st4(sA[pl], pa[pl]);
                st4(sW[pl], pj[pl]);
            }
            __syncthreads();
        }
    }

    const float* SQb = SQ + (size_t)bz * Nn;
#pragma unroll
    for (int j = 0; j < 2; j++) {
        int nj = j0 + wm + j * 16 + rl;
        if (nj >= Nn) continue;
        float sj = SQb[nj];
#pragma unroll
        for (int i = 0; i < 2; i++) {
            int nio = i0 + wn + i * 16 + kq * 4;
            f32x4 a = acc[i][j];
#pragma unroll
            for (int r = 0; r < 4; r++) {
                int ni = nio + r;
                if (ni >= Nn) continue;
                float d = 2.f * a[r] - SQb[ni] - sj;
                NEG[(size_t)ni * Nn + nj] = d;
                if (i0 != j0) NEG[(size_t)nj * Nn + ni] = d;
            }
        }
    }
}

// ---------------------------------------------------------------------------
// MFMA implicit-im2col 3x3 conv (stem L3/L4), r10-proven BN=64 occ-3.
// ---------------------------------------------------------------------------
template <int CIN>
__global__ __launch_bounds__(256, 3)
void mconv6p_k(const unsigned short* __restrict__ T0, const unsigned short* __restrict__ T1,
               const unsigned short* __restrict__ T2,
               const unsigned short* __restrict__ Wc0, const unsigned short* __restrict__ Wc1,
               const unsigned short* __restrict__ Wc2,
               const float* __restrict__ bias, float* __restrict__ out,
               int Cout, int Hin, int Win, int Hout, int Wout, int stride)
{
    const int K = 9 * CIN;
    __shared__ __align__(16) unsigned lA[3][64 * 18];
    __shared__ __align__(16) unsigned lW[3][64 * 18];
    int bz = blockIdx.z;
    int n0 = blockIdx.x * 64, m0 = blockIdx.y * 64;
    int HWo = Hout * Wout;
    int tid = threadIdx.x, wave = tid >> 6, lane = tid & 63;
    int wn = (wave & 1) * 32, wm = (wave >> 1) * 32;
    int rl = lane & 15, kq = lane >> 4;

    f32x4 acc[2][2] = {};

    const unsigned* Tg[3] = {(const unsigned*)T0, (const unsigned*)T1, (const unsigned*)T2};
    const unsigned* Wg[3] = {(const unsigned*)Wc0, (const unsigned*)Wc1, (const unsigned*)Wc2};

    int ar = tid >> 2, ah = tid & 3;
    int s = n0 + ar; if (s >= HWo) s = HWo - 1;
    int ho = s / Wout, wo = s % Wout;
    unsigned* sA[3];
#pragma unroll
    for (int pl = 0; pl < 3; pl++) sA[pl] = &lA[pl][ar * 18 + ah * 4];

    int wr_ = tid >> 2, wo_ = (tid & 3) * 4;
    size_t wbase = ((size_t)(m0 + wr_) * K) >> 1;
    unsigned* sW[3];
#pragma unroll
    for (int pl = 0; pl < 3; pl++) sW[pl] = &lW[pl][wr_ * 18 + wo_];
    size_t HWi = (size_t)Hin * Win;

    uint4 pa[3], pw[3];

    auto loadS = [&](int ks) {
        int kk = ks * 32;
        int tap = kk / CIN;
        int kh = tap / 3, kw = tap % 3;
        int hi = ho * stride - 1 + kh;
        int wi = wo * stride - 1 + kw;
        bool ok = (hi >= 0 && hi < Hin && wi >= 0 && wi < Win);
        if (ok) {
            size_t base = (((size_t)bz * HWi + (size_t)(hi * Win + wi)) * CIN + (kk % CIN)) >> 1;
#pragma unroll
            for (int pl = 0; pl < 3; pl++)
                pa[pl] = *(const uint4*)(Tg[pl] + base + ah * 4);
        } else {
            uint4 z; z.x = 0; z.y = 0; z.z = 0; z.w = 0;
#pragma unroll
            for (int pl = 0; pl < 3; pl++) pa[pl] = z;
        }
#pragma unroll
        for (int pl = 0; pl < 3; pl++)
            pw[pl] = *(const uint4*)(Wg[pl] + wbase + ks * 16 + wo_);
    };
    auto stS = [&]() {
#pragma unroll
        for (int pl = 0; pl < 3; pl++) {
            st4(sA[pl], pa[pl]);
            st4(sW[pl], pw[pl]);
        }
    };

    int nst = K >> 5;
    loadS(0);
    stS();
    __syncthreads();

    for (int ks = 0; ks < nst; ks++) {
        bool more = (ks + 1) < nst;
        if (more) loadS(ks + 1);
        short8b a0[2], a1[2], a2[2];
#pragma unroll
        for (int i = 0; i < 2; i++) {
            int ra = wn + i * 16 + rl;
            a0[i] = ldfrag(lA[0], ra, kq);
            a1[i] = ldfrag(lA[1], ra, kq);
            a2[i] = ldfrag(lA[2], ra, kq);
        }
        short8b w0[2], w1[2], w2[2];
#pragma unroll
        for (int j = 0; j < 2; j++) {
            int rw = wm + j * 16 + rl;
            w0[j] = ldfrag(lW[0], rw, kq);
            w1[j] = ldfrag(lW[1], rw, kq);
            w2[j] = ldfrag(lW[2], rw, kq);
        }
#pragma unroll
        for (int i = 0; i < 2; i++) {
#pragma unroll
            for (int j = 0; j < 2; j++) {
                MFMA6(acc[i][j], a0[i], a1[i], a2[i], w0[j], w1[j], w2[j]);
            }
        }
        __syncthreads();
        if (more) {
            stS();
            __syncthreads();
        }
    }

#pragma unroll
    for (int j = 0; j < 2; j++) {
        int mm = m0 + wm + j * 16 + rl;
        float bs = bias[mm];
#pragma unroll
        for (int i = 0; i < 2; i++) {
            int tn = n0 + wn + i * 16 + kq * 4;
            f32x4 a = acc[i][j];
#pragma unroll
            for (int r = 0; r < 4; r++) {
                int gn2 = tn + r;
                if (gn2 < HWo)
                    out[((size_t)bz * Cout + mm) * HWo + gn2] = a[r] + bs;
            }
        }
    }
}

// ---------------------------------------------------------------------------
// posadd + transpose — unchanged
// ---------------------------------------------------------------------------
__global__ __launch_bounds__(256)
void posadd_k(const float* __restrict__ xin, unsigned short* __restrict__ X0,
              unsigned short* __restrict__ X1, unsigned short* __restrict__ X2)
{
    __shared__ float tile[64][65];
    int t0 = blockIdx.x * 64, c0 = blockIdx.y * 64, b = blockIdx.z;
    int tid = threadIdx.x;
    int tl = tid & 63;
    const float* inb = xin + (size_t)b * 256 * 2500;
#pragma unroll
    for (int p = 0; p < 16; p++) {
        int c = (tid >> 6) + p * 4;
        int t = t0 + tl;
        tile[c][tl] = (t < 2500) ? inb[(size_t)(c0 + c) * 2500 + t] : 0.f;
    }
    __syncthreads();
#pragma unroll
    for (int p = 0; p < 16; p++) {
        int tt = (tid >> 6) + p * 4;
        int t = t0 + tt;
        if (t >= 2500) continue;
        int ch = c0 + tl;
        int yy = t / 50, xx = t % 50;
        int cc = ch & 127;
        double v = (double)((ch < 128) ? (yy + 1) : (xx + 1));
        v = v * (6.283185307179586476925287 / 50.0);
        double e = (double)(2 * (cc >> 1)) / 128.0;
        double d = pow(10000.0, e);
        double a = v / d;
        double pp = (cc & 1) ? cos(a) : sin(a);
        float val = tile[tl][tt] + (float)pp;
        size_t off = ((size_t)b * 2500 + t) * 256 + ch;
        unsigned pm = pack2(val);
        X0[off] = (unsigned short)(pm >> 16);
        X1[off] = (unsigned short)(pm & 0xFFFFu);
        X2[off] = (unsigned short)bf16r(val - unpk(pm));
    }
}

// ---------------------------------------------------------------------------
// Per-token normalize (double accumulation) — unchanged
// ---------------------------------------------------------------------------
__global__ __launch_bounds__(256)
void tok_k(const unsigned short* __restrict__ H0, const unsigned short* __restrict__ H1,
           const unsigned short* __restrict__ H2, unsigned short* __restrict__ T0,
           unsigned short* __restrict__ T1, unsigned short* __restrict__ T2,
           float* __restrict__ SQ)
{
    int wave = threadIdx.x >> 6, lane = threadIdx.x & 63;
    int t = blockIdx.x * 4 + wave;
    int b = blockIdx.y;
    size_t base = ((size_t)b * 2500 + t) * 128;   // u32 pair index
    const unsigned* h0 = (const unsigned*)H0 + base;
    const unsigned* h1 = (const unsigned*)H1 + base;
    const unsigned* h2 = (const unsigned*)H2 + base;
    float v[4];
    double s = 0.0;
#pragma unroll
    for (int g = 0; g < 2; g++) {
        unsigned ua = h0[lane + g * 64], ub = h1[lane + g * 64], uc = h2[lane + g * 64];
        float lo = (__uint_as_float(ua << 16) + __uint_as_float(ub << 16)) + __uint_as_float(uc << 16);
        float hi = (__uint_as_float(ua & 0xFFFF0000u) + __uint_as_float(ub & 0xFFFF0000u)) + __uint_as_float(uc & 0xFFFF0000u);
        v[2 * g] = lo; v[2 * g + 1] = hi;
        s += (double)lo * lo + (double)hi * hi;
    }
#pragma unroll
    for (int off = 32; off > 0; off >>= 1) s += __shfl_xor(s, off);
    float r = (float)(1.0 / sqrt(s + 1e-12));
    unsigned* t0 = (unsigned*)T0 + base;
    unsigned* t1 = (unsigned*)T1 + base;
    unsigned* t2 = (unsigned*)T2 + base;
    double s2 = 0.0;
#pragma unroll
    for (int g = 0; g < 2; g++) {
        float x0 = v[2 * g] * r, x1 = v[2 * g + 1] * r;
        s2 += (double)x0 * x0 + (double)x1 * x1;
        unsigned p0 = pack2(x0), p1 = pack2(x1);
        t0[lane + g * 64] = (p0 >> 16) | (p1 & 0xFFFF0000u);
        t1[lane + g * 64] = (p0 & 0xFFFFu) | (p1 << 16);
        t2[lane + g * 64] = bf16r(x0 - unpk(p0)) | (bf16r(x1 - unpk(p1)) << 16);
    }
#pragma unroll
    for (int off = 32; off > 0; off >>= 1) s2 += __shfl_xor(s2, off);
    if (lane == 0) SQ[b * 2500 + t] = (float)s2;
}

// ---------------------------------------------------------------------------
// top-(k*dil): one wave per row — unchanged
// ---------------------------------------------------------------------------
DEVI unsigned long long pack_key(float x, unsigned idx)
{
    unsigned u = __float_as_uint(x);
    u = (u & 0x80000000u) ? ~u : (u | 0x80000000u);
    return ((unsigned long long)u << 32) | (unsigned long long)(0xFFFFFFFFu - idx);
}

__global__ __launch_bounds__(128)
void topk_k(const float* __restrict__ NEGc, int* __restrict__ IDX,
            int rows, int kd, int dil, int kout, int bz)
{
    __shared__ float vals[2][2560];
    int wave = threadIdx.x >> 6;
    int lane = threadIdx.x & 63;
    int i = blockIdx.x * 2 + wave;
    if (i >= rows) return;
    const float* row = NEGc + (size_t)i * 2500;
    float* v = vals[wave];
    for (int j = lane; j < 2560; j += 64)
        v[j] = (j < 2500) ? (row[j] + 0.0f) : -INFINITY;
    unsigned long long key = pack_key(-INFINITY, 0xFFFFFFFFu);
    for (int q = 0; q < 40; q++) {
        int pos = lane * 40 + q;
        unsigned long long k2 = pack_key(v[pos], (unsigned)pos);
        if (k2 > key) key = k2;
    }
    for (int t = 0; t < kd; t++) {
        unsigned long long r = key;
#pragma unroll
        for (int off = 32; off > 0; off >>= 1) {
            unsigned long long o = __shfl_xor(r, off);
            if (o > r) r = o;
        }
        int sel = (int)(0xFFFFFFFFu - (unsigned)(r & 0xFFFFFFFFull));
        if ((unsigned)sel >= 2500u) sel = 0;
        if (lane == 0 && t % dil == 0)
            IDX[(size_t)(bz * 2500 + i) * kout + t / dil] = sel;
        int lo = sel / 40;
        if (lane == lo) v[sel] = -INFINITY;
        int pos = lo * 40 + lane;
        float x = (lane < 40) ? v[pos] : -INFINITY;
        unsigned long long k2 = pack_key(x, (lane < 40) ? (unsigned)pos : 0xFFFFFFFFu);
#pragma unroll
        for (int off = 32; off > 0; off >>= 1) {
            unsigned long long o = __shfl_xor(k2, off);
            if (o > k2) k2 = o;
        }
        if (lane == lo) key = k2;
    }
}

// ---------------------------------------------------------------------------
// Gather neighbors — unchanged
// ---------------------------------------------------------------------------
__global__ __launch_bounds__(256)
void gather_k(const unsigned short* __restrict__ H0, const unsigned short* __restrict__ H1,
              const unsigned short* __restrict__ H2, const int* __restrict__ IDX,
              unsigned short* __restrict__ F0, unsigned short* __restrict__ F1,
              unsigned short* __restrict__ F2, int k)
{
    int t = blockIdx.x;
    int b = blockIdx.y;
    int q = threadIdx.x;
    __shared__ int idx[18];
    if (q < k) {
        int ii = IDX[((size_t)b * 2500 + t) * k + q];
        if ((unsigned)ii >= 2500u) ii = 0;
        idx[q] = ii;
    }
    __syncthreads();
    size_t base = (size_t)b * 2500 * 256;
    size_t co = base + (size_t)t * 256 + q;
    float center = (bf2f(H0[co]) + bf2f(H1[co])) + bf2f(H2[co]);
    float mx = -INFINITY;
    for (int kk = 0; kk < k; kk++) {
        size_t no = base + (size_t)idx[kk] * 256 + q;
        float v = (bf2f(H0[no]) + bf2f(H1[no])) + bf2f(H2[no]);
        mx = fmaxf(mx, v - center);
    }
    unsigned pc = pack2(center), pd = pack2(mx);
    size_t fo = (size_t)b * 2500 * 256 + (size_t)t * 256 + q;  // u32 pair index
    ((unsigned*)F0)[fo] = (pc >> 16) | (pd & 0xFFFF0000u);
    ((unsigned*)F1)[fo] = (pc & 0xFFFFu) | (pd << 16);
    ((unsigned*)F2)[fo] = bf16r(center - unpk(pc)) | (bf16r(mx - unpk(pd)) << 16);
}

// ---------------------------------------------------------------------------
// Final transpose — unchanged
// ---------------------------------------------------------------------------
__global__ __launch_bounds__(256)
void outt_k(const unsigned short* __restrict__ X0, const unsigned short* __restrict__ X1,
            const unsigned short* __restrict__ X2, float* __restrict__ out)
{
    __shared__ float tile[64][65];
    int t0 = blockIdx.x * 64, c0 = blockIdx.y * 64, b = blockIdx.z;
    int tid = threadIdx.x;
    int tl = tid & 63;
#pragma unroll
    for (int p = 0; p < 16; p++) {
        int tt = (tid >> 6) + p * 4;
        int t = t0 + tt;
        int tc = (t < 2500) ? t : 2499;
        size_t off = ((size_t)b * 2500 + tc) * 256 + c0 + tl;
        tile[tl][tt] = (bf2f(X0[off]) + bf2f(X1[off])) + bf2f(X2[off]);
    }
    __syncthreads();
#pragma unroll
    for (int p = 0; p < 16; p++) {
        int cc = (tid >> 6) + p * 4;
        int t = t0 + tl;
        if (t < 2500)
            out[((size_t)b * 256 + c0 + cc) * 2500 + t] = tile[cc][tl];
    }
}

// ---------------------------------------------------------------------------
extern "C" void kernel_launch(void* const* d_in, const int* in_sizes, int n_in,
                              void* d_out, int out_size, void* d_ws, size_t ws_size,
                              hipStream_t stream)
{
    (void)in_sizes; (void)n_in; (void)out_size; (void)ws_size;
    const float* x_in = (const float*)d_in[0];
    const float *swp[5], *sbp[5], *sgp[5], *sbep[5];
    for (int i = 0; i < 5; i++) {
        swp[i] = (const float*)d_in[1 + 4 * i];
        sbp[i] = (const float*)d_in[2 + 4 * i];
        sgp[i] = (const float*)d_in[3 + 4 * i];
        sbep[i] = (const float*)d_in[4 + 4 * i];
    }
    const float* fc1_w = (const float*)d_in[21];
    const float* fc1_b = (const float*)d_in[22];
    const float* fc1_g = (const float*)d_in[23];
    const float* fc1_be = (const float*)d_in[24];
    const float* mr_w = (const float*)d_in[25];
    const float* mr_g = (const float*)d_in[26];
    const float* mr_be = (const float*)d_in[27];
    const float* fc2_w = (const float*)d_in[28];
    const float* fc2_b = (const float*)d_in[29];
    const float* fc2_g = (const float*)d_in[30];
    const float* fc2_be = (const float*)d_in[31];
    const float* ffn1_w = (const float*)d_in[32];
    const float* ffn1_b = (const float*)d_in[33];
    const float* ffn1_g = (const float*)d_in[34];
    const float* ffn1_be = (const float*)d_in[35];
    const float* ffn2_w = (const float*)d_in[36];
    const float* ffn2_b = (const float*)d_in[37];
    const float* ffn2_g = (const float*)d_in[38];
    const float* ffn2_be = (const float*)d_in[39];

    float* ws = (float*)d_ws;
    // ---- workspace layout (float units; r6-proven) ----
    const size_t NEG_F = 1920000;
    const size_t G_F   = 3840000;
    const size_t TI_F  = 3000000;      // stem-only, dead by main loop
    const size_t CW_F  = 10300000;
    const size_t X_F   = 12500000;
    const size_t HF_F  = 14420000;
    const size_t W_F   = 16340000;
    const size_t SQ_F  = 17815000;
    const size_t PART_F = 17820000;
    const size_t FIN_F = 17829000;
    const size_t IDX_F = 17830000;

    float* ping = ws;
    float* pong = ws + X_F;
    float* NEG  = ws + NEG_F;
    unsigned short* HT0 = (unsigned short*)ws;            // HTn planes
    unsigned short* HT1 = HT0 + 1280000;
    unsigned short* HT2 = HT0 + 2560000;
    unsigned short* Fp0 = (unsigned short*)ws;            // F planes
    unsigned short* Fp1 = Fp0 + 2560000;
    unsigned short* Fp2 = Fp0 + 5120000;
    unsigned short* Gp0 = (unsigned short*)(ws + G_F);    // G planes
    unsigned short* Gp1 = Gp0 + 2560000;
    unsigned short* Gp2 = Gp0 + 5120000;
    unsigned short* H20 = (unsigned short*)ws;            // HF2 planes
    unsigned short* H21 = H20 + 5120000;
    unsigned short* H22 = H20 + 10240000;
    unsigned short* TI0 = (unsigned short*)(ws + TI_F);   // stem split-T planes
    unsigned short* CW0 = (unsigned short*)(ws + CW_F);
    unsigned short* X0 = (unsigned short*)(ws + X_F);
    unsigned short* X1 = X0 + 1280000;
    unsigned short* X2 = X0 + 2560000;
    unsigned short* HF0 = (unsigned short*)(ws + HF_F);
    unsigned short* HF1 = HF0 + 1280000;
    unsigned short* HF2b = HF0 + 2560000;
    unsigned short* W0 = (unsigned short*)(ws + W_F);
    unsigned short* W1 = W0 + 983040;
    unsigned short* W2 = W0 + 1966080;
    float* SQ = ws + SQ_F;
    double* PART = (double*)(ws + PART_F);
    float* FIN = ws + FIN_F;
    int* IDX = (int*)(ws + IDX_F);

    // ---------------- stem ----------------
    int Co[5] = {32, 64, 128, 256, 256};
    int Ho[5] = {400, 200, 100, 50, 50};
    int Ssub[5] = {8, 8, 4, 2, 2};
    float* cur = nullptr;
    for (int l = 0; l < 5; l++) {
        float* outb = (l % 2 == 0) ? ping : pong;
        int HWo = Ho[l] * Ho[l];
        switch (l) {
        case 0:
            conv3x3_t<3, 32><<<dim3(1, 625, 2), 256, 0, stream>>>(
                x_in, swp[0], sbp[0], outb, 32, 800, 800, 400, 400, 2);
            break;
        case 1:
            conv3x3_t<32, 32><<<dim3(2, 157, 2), 256, 0, stream>>>(
                cur, swp[1], sbp[1], outb, 64, 400, 400, 200, 200, 2);
            break;
        case 2:
            conv3x3_t<64, 16><<<dim3(8, 40, 2), 256, 0, stream>>>(
                cur, swp[2], sbp[2], outb, 128, 200, 200, 100, 100, 2);
            break;
        case 3: {
            int psz = 2 * 10000 * 128;
            splitT_k<<<dim3(157, 2, 2), 256, 0, stream>>>(
                cur, TI0, TI0 + psz, TI0 + 2 * psz, 128, 10000);
            int tot = 256 * 1152;
            wconvp_k<<<(tot + 255) / 256, 256, 0, stream>>>(
                swp[3], CW0, CW0 + tot, CW0 + 2 * tot, 128, tot);
            mconv6p_k<128><<<dim3(40, 4, 2), 256, 0, stream>>>(
                TI0, TI0 + psz, TI0 + 2 * psz, CW0, CW0 + tot, CW0 + 2 * tot,
                sbp[3], outb, 256, 100, 100, 50, 50, 2);
            break;
        }
        case 4: {
            int psz = 2 * 2500 * 256;
            splitT_k<<<dim3(40, 4, 2), 256, 0, stream>>>(
                cur, TI0, TI0 + psz, TI0 + 2 * psz, 256, 2500);
            int tot = 256 * 2304;
            wconvp_k<<<(tot + 255) / 256, 256, 0, stream>>>(
                swp[4], CW0, CW0 + tot, CW0 + 2 * tot, 256, tot);
            mconv6p_k<256><<<dim3(40, 4, 2), 256, 0, stream>>>(
                TI0, TI0 + psz, TI0 + 2 * psz, CW0, CW0 + tot, CW0 + 2 * tot,
                sbp[4], outb, 256, 50, 50, 50, 50, 1);
            break;
        }
        }
        int cpg = Co[l] / 32;
        gn_stats_k<<<dim3(Ssub[l], 32, 2), 256, 0, stream>>>(outb, PART, Co[l], HWo, cpg, Ssub[l]);
        gn_reduce_k<<<1, 64, 0, stream>>>(PART, FIN, Ssub[l], (double)cpg * (double)HWo);
        int total = 2 * Co[l] * HWo;
        gn_apply_k<<<(total + 255) / 256, 256, 0, stream>>>(outb, FIN, sgp[l], sbep[l],
                                                            Co[l], HWo, cpg, (l < 4) ? 1 : 0, total);
        cur = outb;
    }
    posadd_k<<<dim3(40, 4, 2), 256, 0, stream>>>(cur, X0, X1, X2);

    // ---------------- 12 Grapher + FFN blocks ----------------
    const int KS[12] = {9, 9, 10, 11, 12, 13, 13, 14, 15, 16, 17, 18};
    const int DILS[12] = {1, 1, 1, 1, 2, 2, 2, 2, 3, 3, 3, 3};
    const int D = 256, N = 2500;

    for (int i = 0; i < 12; i++) {
        pack5p_k<<<3840, 256, 0, stream>>>(
            fc1_w + (size_t)i * 65536, mr_w + (size_t)i * 262144,
            fc2_w + (size_t)i * 131072, ffn1_w + (size_t)i * 262144,
            ffn2_w + (size_t)i * 262144, W0, W1, W2);

        // fc1 -> HF planes
        mgemm6p_k<2><<<dim3(40, 4, 2), 256, 0, stream>>>(
            X0, X1, X2, W0, W1, W2,
            fc1_b + i * D, fc1_g + i * D, fc1_be + i * D,
            nullptr, nullptr, nullptr, HF0, HF1, HF2b, N, D, D, 0);
        tok_k<<<dim3(625, 2), 256, 0, stream>>>(HF0, HF1, HF2b, HT0, HT1, HT2, SQ);
        for (int bz = 0; bz < 2; bz++) {
            mdist6p_k<<<dim3(820, 1, 1), 256, 0, stream>>>(HT0, HT1, HT2, SQ, NEG, N, D, bz);
            topk_k<<<dim3(1250, 1, 1), 128, 0, stream>>>(NEG, IDX, N,
                                                         KS[i] * DILS[i], DILS[i], KS[i], bz);
        }
        gather_k<<<dim3(2500, 2), 256, 0, stream>>>(HF0, HF1, HF2b, IDX, Fp0, Fp1, Fp2, KS[i]);
        // mr -> G planes
        mgemm6p_k<4><<<dim3(40, 4, 2), 256, 0, stream>>>(
            Fp0, Fp1, Fp2, W0 + 65536, W1 + 65536, W2 + 65536,
            nullptr, mr_g + i * 512, mr_be + i * 512,
            nullptr, nullptr, nullptr, Gp0, Gp1, Gp2, N, 512, 512, 1);
        // fc2 + residual -> X planes
        mgemm6p_k<2><<<dim3(40, 4, 2), 256, 0, stream>>>(
            Gp0, Gp1, Gp2, W0 + 327680, W1 + 327680, W2 + 327680,
            fc2_b + i * D, fc2_g + i * D, fc2_be + i * D,
            X0, X1, X2, X0, X1, X2, N, D, 512, 0);
        // ffn1 -> HF2 planes
        mgemm6p_k<4><<<dim3(40, 8, 2), 256, 0, stream>>>(
            X0, X1, X2, W0 + 458752, W1 + 458752, W2 + 458752,
            ffn1_b + i * 1024, ffn1_g + i * 1024, ffn1_be + i * 1024,
            nullptr, nullptr, nullptr, H20, H21, H22, N, 1024, D, 1);
        // ffn2 + residual -> X planes
        mgemm6p_k<2><<<dim3(40, 4, 2), 256, 0, stream>>>(
            H20, H21, H22, W0 + 720896, W1 + 720896, W2 + 720896,
            ffn2_b + i * D, ffn2_g + i * D, ffn2_be + i * D,
            X0, X1, X2, X0, X1, X2, N, D, 1024, 0);
    }

    outt_k<<<dim3(40, 4, 2), 256, 0, stream>>>(X0, X1, X2, (float*)d_out);
}

// Round 13
// 4389.550 us; speedup vs baseline: 1.0506x; 1.0359x over previous
//
#include <hip/hip_runtime.h>
#include <math.h>

#define DEVI static __device__ __forceinline__

typedef __attribute__((ext_vector_type(8))) short short8b;  // 8 bf16 (4 VGPR)
typedef __attribute__((ext_vector_type(4))) float f32x4;

DEVI float gelu_f(float x) { return 0.5f * x * (1.0f + erff(x * 0.70710678118654752440f)); }

// ---- 3-split bf16: x ~= b0 + b1 + b2 (each RN bf16); storage = 3 planes ----
DEVI unsigned pack2(float x)
{
    unsigned xb = __float_as_uint(x);
    unsigned hi = (xb + 0x7FFFu + ((xb >> 16) & 1u)) & 0xFFFF0000u;
    float lof = x - __uint_as_float(hi);
    unsigned lb = __float_as_uint(lof);
    unsigned lo = (lb + 0x7FFFu + ((lb >> 16) & 1u)) >> 16;
    return hi | lo;
}
DEVI float unpk(unsigned u)
{
    return __uint_as_float(u & 0xFFFF0000u) + __uint_as_float(u << 16);
}
DEVI unsigned bf16r(float x)
{
    unsigned b = __float_as_uint(x);
    return (b + 0x7FFFu + ((b >> 16) & 1u)) >> 16;
}
DEVI float bf2f(unsigned short u) { return __uint_as_float((unsigned)u << 16); }

// LDS plane row: 32 bf16 = 16 data u32 + 2 pad = 18 u32 stride (proven r4).
DEVI short8b ldfrag(const unsigned* P, int row, int kq)
{
    const unsigned* b = P + row * 18 + kq * 2;
    union { uint2 h[2]; short8b s; } r;
    r.h[0] = *(const uint2*)(b);
    r.h[1] = *(const uint2*)(b + 8);
    return r.s;
}
DEVI void st8(unsigned* b, uint4 v0, uint4 v1)
{
    uint2 t;
    t.x = v0.x; t.y = v0.y; *(uint2*)(b) = t;
    t.x = v0.z; t.y = v0.w; *(uint2*)(b + 2) = t;
    t.x = v1.x; t.y = v1.y; *(uint2*)(b + 4) = t;
    t.x = v1.z; t.y = v1.w; *(uint2*)(b + 6) = t;
}
DEVI void st4(unsigned* b, uint4 v0)
{
    uint2 t;
    t.x = v0.x; t.y = v0.y; *(uint2*)(b) = t;
    t.x = v0.z; t.y = v0.w; *(uint2*)(b + 2) = t;
}

#define MFMA6(ACC, A0, A1, A2F, W0, W1, W2F) do { \
    ACC = __builtin_amdgcn_mfma_f32_16x16x32_bf16(A2F, W0, ACC, 0, 0, 0); \
    ACC = __builtin_amdgcn_mfma_f32_16x16x32_bf16(A0, W2F, ACC, 0, 0, 0); \
    ACC = __builtin_amdgcn_mfma_f32_16x16x32_bf16(A1, W1, ACC, 0, 0, 0); \
    ACC = __builtin_amdgcn_mfma_f32_16x16x32_bf16(A1, W0, ACC, 0, 0, 0); \
    ACC = __builtin_amdgcn_mfma_f32_16x16x32_bf16(A0, W1, ACC, 0, 0, 0); \
    ACC = __builtin_amdgcn_mfma_f32_16x16x32_bf16(A0, W0, ACC, 0, 0, 0); \
} while (0)

// ---------------------------------------------------------------------------
// Direct 3x3 conv for small Cin (stem L0-L2). r13: XCD-aware bijective
// swizzle — XCD k (fid%8) owns site-instances ≡ k (mod 8); co varies
// SLOWEST per XCD so each XCD re-reads its own (L2-resident) input slice.
// Grid: x = site chunks (padded so S=nsx*nb and T=S*nco are %8==0),
// y = co-groups, z = batch. Pad blocks skip the store via s<HWo guard.
// ---------------------------------------------------------------------------
template <int CIN, int NCO>
__global__ __launch_bounds__(256)
void conv3x3_t(const float* __restrict__ in, const float* __restrict__ w,
               const float* __restrict__ bias, float* __restrict__ out,
               int Cout, int Hin, int Win, int Hout, int Wout, int stride)
{
    __shared__ __align__(16) float wlds[CIN * 9 * NCO];
    int nsx = gridDim.x, nco = gridDim.y;
    int fid = blockIdx.x + nsx * (blockIdx.y + nco * blockIdx.z);
    int S = nsx * gridDim.z;           // site-instances (site chunk, batch)
    int sPer = S >> 3;                 // per-XCD site-instances (S % 8 == 0)
    int k8 = fid & 7, j = fid >> 3;
    int site_inst = k8 + 8 * (j % sPer);
    int co_g = j / sPer;
    int sx = site_inst % nsx;
    int b = site_inst / nsx;

    int co0 = co_g * NCO;
    int tid = threadIdx.x;
    int HWo = Hout * Wout;
    int s = sx * 256 + tid;
    int sc = (s < HWo) ? s : (HWo - 1);
    int ho = sc / Wout, wo = sc % Wout;
    float acc[NCO];
#pragma unroll
    for (int jj = 0; jj < NCO; jj++) acc[jj] = bias[co0 + jj];
    const float* inb = in + (size_t)b * CIN * Hin * Win;
    size_t HWi = (size_t)Hin * Win;

    const int nw = NCO * CIN * 9;
    for (int i = tid; i < nw; i += 256) {
        int jj = i % NCO;
        int rest = i / NCO;
        int ci = rest % CIN, tap = rest / CIN;
        wlds[i] = w[((size_t)(co0 + jj) * CIN + ci) * 9 + tap];
    }
    __syncthreads();
    for (int kh = 0; kh < 3; kh++) {
        int hi = ho * stride - 1 + kh;
        bool okh = (hi >= 0 && hi < Hin);
        for (int kw = 0; kw < 3; kw++) {
            int wi = wo * stride - 1 + kw;
            if (!okh || wi < 0 || wi >= Win) continue;
            int tap = kh * 3 + kw;
            const float* ip = inb + (size_t)hi * Win + wi;
            const float* wp = wlds + (size_t)tap * CIN * NCO;
#pragma unroll 4
            for (int ci = 0; ci < CIN; ci++) {
                float xv = ip[(size_t)ci * HWi];
                const float* wq = wp + ci * NCO;
#pragma unroll
                for (int j4 = 0; j4 < NCO; j4 += 4) {
                    float4 wv = *(const float4*)(wq + j4);
                    acc[j4 + 0] += xv * wv.x; acc[j4 + 1] += xv * wv.y;
                    acc[j4 + 2] += xv * wv.z; acc[j4 + 3] += xv * wv.w;
                }
            }
        }
    }
    if (s < HWo) {
        size_t ob = ((size_t)b * Cout + co0) * HWo + s;
#pragma unroll
        for (int jj = 0; jj < NCO; jj++) out[ob + (size_t)jj * HWo] = acc[jj];
    }
}

// ---------------------------------------------------------------------------
// GroupNorm (deterministic) — unchanged
// ---------------------------------------------------------------------------
__global__ __launch_bounds__(256)
void gn_stats_k(const float* __restrict__ x, double* __restrict__ part,
                int C, int HW, int cpg, int S)
{
    int srt = blockIdx.x, g = blockIdx.y, b = blockIdx.z;
    long len = (long)cpg * HW;
    long chunk = (len + S - 1) / S;
    long lo = (long)srt * chunk;
    long hi = lo + chunk; if (hi > len) hi = len;
    const float* xp = x + ((size_t)b * C + (size_t)g * cpg) * HW;
    double s1 = 0.0, s2 = 0.0;
    for (long i = lo + threadIdx.x; i < hi; i += 256) {
        double v = (double)xp[i];
        s1 += v; s2 += v * v;
    }
    __shared__ double r1[256], r2[256];
    r1[threadIdx.x] = s1; r2[threadIdx.x] = s2;
    __syncthreads();
    for (int t = 128; t > 0; t >>= 1) {
        if (threadIdx.x < t) { r1[threadIdx.x] += r1[threadIdx.x + t]; r2[threadIdx.x] += r2[threadIdx.x + t]; }
        __syncthreads();
    }
    if (threadIdx.x == 0) {
        size_t slot = ((size_t)(b * 32 + g) * S + srt) * 2;
        part[slot] = r1[0];
        part[slot + 1] = r2[0];
    }
}

__global__ __launch_bounds__(64)
void gn_reduce_k(const double* __restrict__ part, float* __restrict__ fin,
                 int S, double cnt)
{
    int t = threadIdx.x;
    double s1 = 0.0, s2 = 0.0;
    for (int s = 0; s < S; s++) {
        size_t slot = ((size_t)t * S + s) * 2;
        s1 += part[slot];
        s2 += part[slot + 1];
    }
    double m = s1 / cnt;
    double var = s2 / cnt - m * m;
    double inv = 1.0 / sqrt(var + 1e-5);
    fin[t * 2] = (float)m;
    fin[t * 2 + 1] = (float)inv;
}

__global__ __launch_bounds__(256)
void gn_apply_k(float* __restrict__ x, const float* __restrict__ fin,
                const float* __restrict__ gma, const float* __restrict__ bta,
                int C, int HW, int cpg, int do_gelu, int total)
{
    int idx = blockIdx.x * 256 + threadIdx.x;
    if (idx >= total) return;
    int c = (idx / HW) % C;
    int b = idx / (HW * C);
    int g = c / cpg;
    float m = fin[(b * 32 + g) * 2];
    float inv = fin[(b * 32 + g) * 2 + 1];
    float v = (x[idx] - m) * inv * gma[c] + bta[c];
    if (do_gelu) v = gelu_f(v);
    x[idx] = v;
}

// ---------------------------------------------------------------------------
// Transpose+split stem input: in[b][c][hw] fp32 -> 3 planes [b][hw][c] bf16
// ---------------------------------------------------------------------------
__global__ __launch_bounds__(256)
void splitT_k(const float* __restrict__ in, unsigned short* __restrict__ P0,
              unsigned short* __restrict__ P1, unsigned short* __restrict__ P2,
              int C, int HW)
{
    __shared__ float tile[64][65];
    int h0 = blockIdx.x * 64, c0 = blockIdx.y * 64, b = blockIdx.z;
    int tid = threadIdx.x;
    int tl = tid & 63;
    const float* inb = in + (size_t)b * C * HW;
#pragma unroll
    for (int p = 0; p < 16; p++) {
        int c = (tid >> 6) + p * 4;
        int h = h0 + tl;
        tile[c][tl] = (h < HW) ? inb[(size_t)(c0 + c) * HW + h] : 0.f;
    }
    __syncthreads();
#pragma unroll
    for (int p = 0; p < 16; p++) {
        int hh = (tid >> 6) + p * 4;
        int h = h0 + hh;
        if (h >= HW) continue;
        int ch = c0 + tl;
        float v = tile[tl][hh];
        unsigned pm = pack2(v);
        size_t off = ((size_t)b * HW + h) * C + ch;
        P0[off] = (unsigned short)(pm >> 16);
        P1[off] = (unsigned short)(pm & 0xFFFFu);
        P2[off] = (unsigned short)bf16r(v - unpk(pm));
    }
}

// ---------------------------------------------------------------------------
// Conv weight pack to 3 planes, k = tap*Cin + ci — unchanged
// ---------------------------------------------------------------------------
__global__ __launch_bounds__(256)
void wconvp_k(const float* __restrict__ w, unsigned short* __restrict__ P0,
              unsigned short* __restrict__ P1, unsigned short* __restrict__ P2,
              int Cin, int total)
{
    int idx = blockIdx.x * 256 + threadIdx.x;
    if (idx >= total) return;
    int K = Cin * 9;
    int co = idx / K, k = idx % K;
    int tap = k / Cin, ci = k - tap * Cin;
    float v = w[((size_t)co * Cin + ci) * 9 + tap];
    unsigned pm = pack2(v);
    P0[idx] = (unsigned short)(pm >> 16);
    P1[idx] = (unsigned short)(pm & 0xFFFFu);
    P2[idx] = (unsigned short)bf16r(v - unpk(pm));
}

// ---------------------------------------------------------------------------
// Main-loop weight pack (fc1|mr|fc2|ffn1|ffn2) to 3 planes — unchanged
// ---------------------------------------------------------------------------
__global__ __launch_bounds__(256)
void pack5p_k(const float* __restrict__ s0, const float* __restrict__ s1,
              const float* __restrict__ s2, const float* __restrict__ s3,
              const float* __restrict__ s4, unsigned short* __restrict__ P0,
              unsigned short* __restrict__ P1, unsigned short* __restrict__ P2)
{
    int idx = blockIdx.x * 256 + threadIdx.x;   // grid exact: 983040
    float v;
    if (idx < 65536)       v = s0[idx];
    else if (idx < 327680) v = s1[idx - 65536];
    else if (idx < 458752) v = s2[idx - 327680];
    else if (idx < 720896) v = s3[idx - 458752];
    else                   v = s4[idx - 720896];
    unsigned pm = pack2(v);
    P0[idx] = (unsigned short)(pm >> 16);
    P1[idx] = (unsigned short)(pm & 0xFFFFu);
    P2[idx] = (unsigned short)bf16r(v - unpk(pm));
}

// ---------------------------------------------------------------------------
// MFMA GEMM, 6-term, plane storage, r10-proven: BN=64, single LDS buffer,
// issue-early register prefetch, occ-3.
// ---------------------------------------------------------------------------
template <int JT>
__global__ __launch_bounds__(256, 3)
void mgemm6p_k(const unsigned short* __restrict__ A0, const unsigned short* __restrict__ A1,
               const unsigned short* __restrict__ A2,
               const unsigned short* __restrict__ W0, const unsigned short* __restrict__ W1,
               const unsigned short* __restrict__ W2,
               const float* __restrict__ bias, const float* __restrict__ gma,
               const float* __restrict__ bta,
               const unsigned short* __restrict__ R0, const unsigned short* __restrict__ R1,
               const unsigned short* __restrict__ R2,
               unsigned short* __restrict__ C0, unsigned short* __restrict__ C1,
               unsigned short* __restrict__ C2,
               int N, int M, int K, int do_gelu)
{
    const int BM = 32 * JT;
    __shared__ __align__(16) unsigned lA[3][64 * 18];
    __shared__ __align__(16) unsigned lW[3][BM * 18];
    int bz = blockIdx.z;
    int n0 = blockIdx.x * 64, m0 = blockIdx.y * BM;
    int tid = threadIdx.x, wave = tid >> 6, lane = tid & 63;
    int wn = (wave & 1) * 32, wm = (wave >> 1) * (16 * JT);
    int rl = lane & 15, kq = lane >> 4;

    f32x4 acc[2][JT] = {};

    const unsigned* Ag[3] = {(const unsigned*)A0, (const unsigned*)A1, (const unsigned*)A2};
    const unsigned* Wg[3] = {(const unsigned*)W0, (const unsigned*)W1, (const unsigned*)W2};

    int ar = tid >> 2, ah = tid & 3;
    int aga = n0 + ar; if (aga >= N) aga = N - 1;
    size_t abase = (((size_t)bz * N + aga) * K) >> 1;
    unsigned* sA[3];
#pragma unroll
    for (int pl = 0; pl < 3; pl++) sA[pl] = &lA[pl][ar * 18 + ah * 4];

    int wr_ = (JT == 4) ? (tid >> 1) : (tid >> 2);
    int wo_ = (JT == 4) ? ((tid & 1) * 8) : ((tid & 3) * 4);
    size_t wbase = ((size_t)(m0 + wr_) * K) >> 1;
    unsigned* sW[3];
#pragma unroll
    for (int pl = 0; pl < 3; pl++) sW[pl] = &lW[pl][wr_ * 18 + wo_];

    uint4 pa[3], pw[3][2];

#pragma unroll
    for (int pl = 0; pl < 3; pl++) {
        pa[pl] = *(const uint4*)(Ag[pl] + abase + ah * 4);
        const unsigned* h = Wg[pl] + wbase + wo_;
        pw[pl][0] = *(const uint4*)(h);
        if (JT == 4) pw[pl][1] = *(const uint4*)(h + 4);
    }
#pragma unroll
    for (int pl = 0; pl < 3; pl++) {
        st4(sA[pl], pa[pl]);
        if (JT == 4) st8(sW[pl], pw[pl][0], pw[pl][1]); else st4(sW[pl], pw[pl][0]);
    }
    __syncthreads();

    for (int k0 = 0; k0 < K; k0 += 32) {
        bool more = (k0 + 32) < K;
        if (more) {
#pragma unroll
            for (int pl = 0; pl < 3; pl++) {
                pa[pl] = *(const uint4*)(Ag[pl] + abase + ((k0 + 32) >> 1) + ah * 4);
                const unsigned* h = Wg[pl] + wbase + ((k0 + 32) >> 1) + wo_;
                pw[pl][0] = *(const uint4*)(h);
                if (JT == 4) pw[pl][1] = *(const uint4*)(h + 4);
            }
        }
        short8b a0[2], a1[2], a2[2];
#pragma unroll
        for (int i = 0; i < 2; i++) {
            int ra = wn + i * 16 + rl;
            a0[i] = ldfrag(lA[0], ra, kq);
            a1[i] = ldfrag(lA[1], ra, kq);
            a2[i] = ldfrag(lA[2], ra, kq);
        }
        short8b w0[JT], w1[JT], w2[JT];
#pragma unroll
        for (int j = 0; j < JT; j++) {
            int rw = wm + j * 16 + rl;
            w0[j] = ldfrag(lW[0], rw, kq);
            w1[j] = ldfrag(lW[1], rw, kq);
            w2[j] = ldfrag(lW[2], rw, kq);
        }
#pragma unroll
        for (int i = 0; i < 2; i++) {
#pragma unroll
            for (int j = 0; j < JT; j++) {
                MFMA6(acc[i][j], a0[i], a1[i], a2[i], w0[j], w1[j], w2[j]);
            }
        }
        __syncthreads();
        if (more) {
#pragma unroll
            for (int pl = 0; pl < 3; pl++) {
                st4(sA[pl], pa[pl]);
                if (JT == 4) st8(sW[pl], pw[pl][0], pw[pl][1]); else st4(sW[pl], pw[pl][0]);
            }
            __syncthreads();
        }
    }

#pragma unroll
    for (int j = 0; j < JT; j++) {
        int mm = m0 + wm + j * 16 + rl;
        float bs = bias ? bias[mm] : 0.f;
        float gm = gma[mm], bt = bta[mm];
#pragma unroll
        for (int i = 0; i < 2; i++) {
            int tn = n0 + wn + i * 16 + kq * 4;
            f32x4 a = acc[i][j];
#pragma unroll
            for (int r = 0; r < 4; r++) {
                int gn2 = tn + r;
                if (gn2 >= N) continue;
                float v = (a[r] + bs) * gm + bt;
                if (do_gelu) v = gelu_f(v);
                size_t off = ((size_t)bz * N + gn2) * M + mm;
                if (R0) v += (bf2f(R0[off]) + bf2f(R1[off])) + bf2f(R2[off]);
                unsigned pm = pack2(v);
                C0[off] = (unsigned short)(pm >> 16);
                C1[off] = (unsigned short)(pm & 0xFFFFu);
                C2[off] = (unsigned short)bf16r(v - unpk(pm));
            }
        }
    }
}

// ---------------------------------------------------------------------------
// MFMA distance syrk, 6-term, upper-tri + mirror, r10-proven 64x64 occ-3.
// ---------------------------------------------------------------------------
__global__ __launch_bounds__(256, 3)
void mdist6p_k(const unsigned short* __restrict__ H0, const unsigned short* __restrict__ H1,
               const unsigned short* __restrict__ H2, const float* __restrict__ SQ,
               float* __restrict__ NEG, int Nn, int K, int bz)
{
    __shared__ __align__(16) unsigned lA[3][64 * 18];
    __shared__ __align__(16) unsigned lW[3][64 * 18];
    int q = blockIdx.x;
    int ti = 0;
    while (q >= 40 - ti) { q -= 40 - ti; ti++; }
    int tj = ti + q;
    int i0 = ti * 64, j0 = tj * 64;
    int tid = threadIdx.x, wave = tid >> 6, lane = tid & 63;
    int wn = (wave & 1) * 32, wm = (wave >> 1) * 32;
    int rl = lane & 15, kq = lane >> 4;

    f32x4 acc[2][2] = {};

    const unsigned* Hg[3] = {(const unsigned*)H0, (const unsigned*)H1, (const unsigned*)H2};

    int ar = tid >> 2, ah = tid & 3;
    int gi = i0 + ar; if (gi >= Nn) gi = Nn - 1;
    int gj = j0 + ar; if (gj >= Nn) gj = Nn - 1;
    size_t ibase = (((size_t)bz * Nn + gi) * K) >> 1;
    size_t jbase = (((size_t)bz * Nn + gj) * K) >> 1;
    unsigned* sA[3];
    unsigned* sW[3];
#pragma unroll
    for (int pl = 0; pl < 3; pl++) {
        sA[pl] = &lA[pl][ar * 18 + ah * 4];
        sW[pl] = &lW[pl][ar * 18 + ah * 4];
    }

    uint4 pa[3], pj[3];
#pragma unroll
    for (int pl = 0; pl < 3; pl++) {
        pa[pl] = *(const uint4*)(Hg[pl] + ibase + ah * 4);
        pj[pl] = *(const uint4*)(Hg[pl] + jbase + ah * 4);
    }
#pragma unroll
    for (int pl = 0; pl < 3; pl++) {
        st4(sA[pl], pa[pl]);
        st4(sW[pl], pj[pl]);
    }
    __syncthreads();

    for (int k0 = 0; k0 < K; k0 += 32) {
        bool more = (k0 + 32) < K;
        if (more) {
#pragma unroll
            for (int pl = 0; pl < 3; pl++) {
                pa[pl] = *(const uint4*)(Hg[pl] + ibase + ((k0 + 32) >> 1) + ah * 4);
                pj[pl] = *(const uint4*)(Hg[pl] + jbase + ((k0 + 32) >> 1) + ah * 4);
            }
        }
        short8b a0[2], a1[2], a2[2], w0[2], w1[2], w2[2];
#pragma unroll
        for (int i = 0; i < 2; i++) {
            int ra = wn + i * 16 + rl;
            a0[i] = ldfrag(lA[0], ra, kq);
            a1[i] = ldfrag(lA[1], ra, kq);
            a2[i] = ldfrag(lA[2], ra, kq);
            int rw = wm + i * 16 + rl;
            w0[i] = ldfrag(lW[0], rw, kq);
            w1[i] = ldfrag(lW[1], rw, kq);
            w2[i] = ldfrag(lW[2], rw, kq);
        }
#pragma unroll
        for (int i = 0; i < 2; i++) {
#pragma unroll
            for (int j = 0; j < 2; j++) {
                MFMA6(acc[i][j], a0[i], a1[i], a2[i], w0[j], w1[j], w2[j]);
            }
        }
        __syncthreads();
        if (more) {
#pragma unroll
            for (int pl = 0; pl < 3; pl++) {
                st4(sA[pl], pa[pl]);
                st4(sW[pl], pj[pl]);
            }
            __syncthreads();
        }
    }

    const float* SQb = SQ + (size_t)bz * Nn;
#pragma unroll
    for (int j = 0; j < 2; j++) {
        int nj = j0 + wm + j * 16 + rl;
        if (nj >= Nn) continue;
        float sj = SQb[nj];
#pragma unroll
        for (int i = 0; i < 2; i++) {
            int nio = i0 + wn + i * 16 + kq * 4;
            f32x4 a = acc[i][j];
#pragma unroll
            for (int r = 0; r < 4; r++) {
                int ni = nio + r;
                if (ni >= Nn) continue;
                float d = 2.f * a[r] - SQb[ni] - sj;
                NEG[(size_t)ni * Nn + nj] = d;
                if (i0 != j0) NEG[(size_t)nj * Nn + ni] = d;
            }
        }
    }
}

// ---------------------------------------------------------------------------
// MFMA implicit-im2col 3x3 conv (stem L3/L4), r10-proven BN=64 occ-3.
// ---------------------------------------------------------------------------
template <int CIN>
__global__ __launch_bounds__(256, 3)
void mconv6p_k(const unsigned short* __restrict__ T0, const unsigned short* __restrict__ T1,
               const unsigned short* __restrict__ T2,
               const unsigned short* __restrict__ Wc0, const unsigned short* __restrict__ Wc1,
               const unsigned short* __restrict__ Wc2,
               const float* __restrict__ bias, float* __restrict__ out,
               int Cout, int Hin, int Win, int Hout, int Wout, int stride)
{
    const int K = 9 * CIN;
    __shared__ __align__(16) unsigned lA[3][64 * 18];
    __shared__ __align__(16) unsigned lW[3][64 * 18];
    int bz = blockIdx.z;
    int n0 = blockIdx.x * 64, m0 = blockIdx.y * 64;
    int HWo = Hout * Wout;
    int tid = threadIdx.x, wave = tid >> 6, lane = tid & 63;
    int wn = (wave & 1) * 32, wm = (wave >> 1) * 32;
    int rl = lane & 15, kq = lane >> 4;

    f32x4 acc[2][2] = {};

    const unsigned* Tg[3] = {(const unsigned*)T0, (const unsigned*)T1, (const unsigned*)T2};
    const unsigned* Wg[3] = {(const unsigned*)Wc0, (const unsigned*)Wc1, (const unsigned*)Wc2};

    int ar = tid >> 2, ah = tid & 3;
    int s = n0 + ar; if (s >= HWo) s = HWo - 1;
    int ho = s / Wout, wo = s % Wout;
    unsigned* sA[3];
#pragma unroll
    for (int pl = 0; pl < 3; pl++) sA[pl] = &lA[pl][ar * 18 + ah * 4];

    int wr_ = tid >> 2, wo_ = (tid & 3) * 4;
    size_t wbase = ((size_t)(m0 + wr_) * K) >> 1;
    unsigned* sW[3];
#pragma unroll
    for (int pl = 0; pl < 3; pl++) sW[pl] = &lW[pl][wr_ * 18 + wo_];
    size_t HWi = (size_t)Hin * Win;

    uint4 pa[3], pw[3];

    auto loadS = [&](int ks) {
        int kk = ks * 32;
        int tap = kk / CIN;
        int kh = tap / 3, kw = tap % 3;
        int hi = ho * stride - 1 + kh;
        int wi = wo * stride - 1 + kw;
        bool ok = (hi >= 0 && hi < Hin && wi >= 0 && wi < Win);
        if (ok) {
            size_t base = (((size_t)bz * HWi + (size_t)(hi * Win + wi)) * CIN + (kk % CIN)) >> 1;
#pragma unroll
            for (int pl = 0; pl < 3; pl++)
                pa[pl] = *(const uint4*)(Tg[pl] + base + ah * 4);
        } else {
            uint4 z; z.x = 0; z.y = 0; z.z = 0; z.w = 0;
#pragma unroll
            for (int pl = 0; pl < 3; pl++) pa[pl] = z;
        }
#pragma unroll
        for (int pl = 0; pl < 3; pl++)
            pw[pl] = *(const uint4*)(Wg[pl] + wbase + ks * 16 + wo_);
    };
    auto stS = [&]() {
#pragma unroll
        for (int pl = 0; pl < 3; pl++) {
            st4(sA[pl], pa[pl]);
            st4(sW[pl], pw[pl]);
        }
    };

    int nst = K >> 5;
    loadS(0);
    stS();
    __syncthreads();

    for (int ks = 0; ks < nst; ks++) {
        bool more = (ks + 1) < nst;
        if (more) loadS(ks + 1);
        short8b a0[2], a1[2], a2[2];
#pragma unroll
        for (int i = 0; i < 2; i++) {
            int ra = wn + i * 16 + rl;
            a0[i] = ldfrag(lA[0], ra, kq);
            a1[i] = ldfrag(lA[1], ra, kq);
            a2[i] = ldfrag(lA[2], ra, kq);
        }
        short8b w0[2], w1[2], w2[2];
#pragma unroll
        for (int j = 0; j < 2; j++) {
            int rw = wm + j * 16 + rl;
            w0[j] = ldfrag(lW[0], rw, kq);
            w1[j] = ldfrag(lW[1], rw, kq);
            w2[j] = ldfrag(lW[2], rw, kq);
        }
#pragma unroll
        for (int i = 0; i < 2; i++) {
#pragma unroll
            for (int j = 0; j < 2; j++) {
                MFMA6(acc[i][j], a0[i], a1[i], a2[i], w0[j], w1[j], w2[j]);
            }
        }
        __syncthreads();
        if (more) {
            stS();
            __syncthreads();
        }
    }

#pragma unroll
    for (int j = 0; j < 2; j++) {
        int mm = m0 + wm + j * 16 + rl;
        float bs = bias[mm];
#pragma unroll
        for (int i = 0; i < 2; i++) {
            int tn = n0 + wn + i * 16 + kq * 4;
            f32x4 a = acc[i][j];
#pragma unroll
            for (int r = 0; r < 4; r++) {
                int gn2 = tn + r;
                if (gn2 < HWo)
                    out[((size_t)bz * Cout + mm) * HWo + gn2] = a[r] + bs;
            }
        }
    }
}

// ---------------------------------------------------------------------------
// posadd + transpose — unchanged
// ---------------------------------------------------------------------------
__global__ __launch_bounds__(256)
void posadd_k(const float* __restrict__ xin, unsigned short* __restrict__ X0,
              unsigned short* __restrict__ X1, unsigned short* __restrict__ X2)
{
    __shared__ float tile[64][65];
    int t0 = blockIdx.x * 64, c0 = blockIdx.y * 64, b = blockIdx.z;
    int tid = threadIdx.x;
    int tl = tid & 63;
    const float* inb = xin + (size_t)b * 256 * 2500;
#pragma unroll
    for (int p = 0; p < 16; p++) {
        int c = (tid >> 6) + p * 4;
        int t = t0 + tl;
        tile[c][tl] = (t < 2500) ? inb[(size_t)(c0 + c) * 2500 + t] : 0.f;
    }
    __syncthreads();
#pragma unroll
    for (int p = 0; p < 16; p++) {
        int tt = (tid >> 6) + p * 4;
        int t = t0 + tt;
        if (t >= 2500) continue;
        int ch = c0 + tl;
        int yy = t / 50, xx = t % 50;
        int cc = ch & 127;
        double v = (double)((ch < 128) ? (yy + 1) : (xx + 1));
        v = v * (6.283185307179586476925287 / 50.0);
        double e = (double)(2 * (cc >> 1)) / 128.0;
        double d = pow(10000.0, e);
        double a = v / d;
        double pp = (cc & 1) ? cos(a) : sin(a);
        float val = tile[tl][tt] + (float)pp;
        size_t off = ((size_t)b * 2500 + t) * 256 + ch;
        unsigned pm = pack2(val);
        X0[off] = (unsigned short)(pm >> 16);
        X1[off] = (unsigned short)(pm & 0xFFFFu);
        X2[off] = (unsigned short)bf16r(val - unpk(pm));
    }
}

// ---------------------------------------------------------------------------
// Per-token normalize (double accumulation) — unchanged
// ---------------------------------------------------------------------------
__global__ __launch_bounds__(256)
void tok_k(const unsigned short* __restrict__ H0, const unsigned short* __restrict__ H1,
           const unsigned short* __restrict__ H2, unsigned short* __restrict__ T0,
           unsigned short* __restrict__ T1, unsigned short* __restrict__ T2,
           float* __restrict__ SQ)
{
    int wave = threadIdx.x >> 6, lane = threadIdx.x & 63;
    int t = blockIdx.x * 4 + wave;
    int b = blockIdx.y;
    size_t base = ((size_t)b * 2500 + t) * 128;   // u32 pair index
    const unsigned* h0 = (const unsigned*)H0 + base;
    const unsigned* h1 = (const unsigned*)H1 + base;
    const unsigned* h2 = (const unsigned*)H2 + base;
    float v[4];
    double s = 0.0;
#pragma unroll
    for (int g = 0; g < 2; g++) {
        unsigned ua = h0[lane + g * 64], ub = h1[lane + g * 64], uc = h2[lane + g * 64];
        float lo = (__uint_as_float(ua << 16) + __uint_as_float(ub << 16)) + __uint_as_float(uc << 16);
        float hi = (__uint_as_float(ua & 0xFFFF0000u) + __uint_as_float(ub & 0xFFFF0000u)) + __uint_as_float(uc & 0xFFFF0000u);
        v[2 * g] = lo; v[2 * g + 1] = hi;
        s += (double)lo * lo + (double)hi * hi;
    }
#pragma unroll
    for (int off = 32; off > 0; off >>= 1) s += __shfl_xor(s, off);
    float r = (float)(1.0 / sqrt(s + 1e-12));
    unsigned* t0 = (unsigned*)T0 + base;
    unsigned* t1 = (unsigned*)T1 + base;
    unsigned* t2 = (unsigned*)T2 + base;
    double s2 = 0.0;
#pragma unroll
    for (int g = 0; g < 2; g++) {
        float x0 = v[2 * g] * r, x1 = v[2 * g + 1] * r;
        s2 += (double)x0 * x0 + (double)x1 * x1;
        unsigned p0 = pack2(x0), p1 = pack2(x1);
        t0[lane + g * 64] = (p0 >> 16) | (p1 & 0xFFFF0000u);
        t1[lane + g * 64] = (p0 & 0xFFFFu) | (p1 << 16);
        t2[lane + g * 64] = bf16r(x0 - unpk(p0)) | (bf16r(x1 - unpk(p1)) << 16);
    }
#pragma unroll
    for (int off = 32; off > 0; off >>= 1) s2 += __shfl_xor(s2, off);
    if (lane == 0) SQ[b * 2500 + t] = (float)s2;
}

// ---------------------------------------------------------------------------
// top-(k*dil): one wave per row — unchanged
// ---------------------------------------------------------------------------
DEVI unsigned long long pack_key(float x, unsigned idx)
{
    unsigned u = __float_as_uint(x);
    u = (u & 0x80000000u) ? ~u : (u | 0x80000000u);
    return ((unsigned long long)u << 32) | (unsigned long long)(0xFFFFFFFFu - idx);
}

__global__ __launch_bounds__(128)
void topk_k(const float* __restrict__ NEGc, int* __restrict__ IDX,
            int rows, int kd, int dil, int kout, int bz)
{
    __shared__ float vals[2][2560];
    int wave = threadIdx.x >> 6;
    int lane = threadIdx.x & 63;
    int i = blockIdx.x * 2 + wave;
    if (i >= rows) return;
    const float* row = NEGc + (size_t)i * 2500;
    float* v = vals[wave];
    for (int j = lane; j < 2560; j += 64)
        v[j] = (j < 2500) ? (row[j] + 0.0f) : -INFINITY;
    unsigned long long key = pack_key(-INFINITY, 0xFFFFFFFFu);
    for (int q = 0; q < 40; q++) {
        int pos = lane * 40 + q;
        unsigned long long k2 = pack_key(v[pos], (unsigned)pos);
        if (k2 > key) key = k2;
    }
    for (int t = 0; t < kd; t++) {
        unsigned long long r = key;
#pragma unroll
        for (int off = 32; off > 0; off >>= 1) {
            unsigned long long o = __shfl_xor(r, off);
            if (o > r) r = o;
        }
        int sel = (int)(0xFFFFFFFFu - (unsigned)(r & 0xFFFFFFFFull));
        if ((unsigned)sel >= 2500u) sel = 0;
        if (lane == 0 && t % dil == 0)
            IDX[(size_t)(bz * 2500 + i) * kout + t / dil] = sel;
        int lo = sel / 40;
        if (lane == lo) v[sel] = -INFINITY;
        int pos = lo * 40 + lane;
        float x = (lane < 40) ? v[pos] : -INFINITY;
        unsigned long long k2 = pack_key(x, (lane < 40) ? (unsigned)pos : 0xFFFFFFFFu);
#pragma unroll
        for (int off = 32; off > 0; off >>= 1) {
            unsigned long long o = __shfl_xor(k2, off);
            if (o > k2) k2 = o;
        }
        if (lane == lo) key = k2;
    }
}

// ---------------------------------------------------------------------------
// Gather neighbors — unchanged
// ---------------------------------------------------------------------------
__global__ __launch_bounds__(256)
void gather_k(const unsigned short* __restrict__ H0, const unsigned short* __restrict__ H1,
              const unsigned short* __restrict__ H2, const int* __restrict__ IDX,
              unsigned short* __restrict__ F0, unsigned short* __restrict__ F1,
              unsigned short* __restrict__ F2, int k)
{
    int t = blockIdx.x;
    int b = blockIdx.y;
    int q = threadIdx.x;
    __shared__ int idx[18];
    if (q < k) {
        int ii = IDX[((size_t)b * 2500 + t) * k + q];
        if ((unsigned)ii >= 2500u) ii = 0;
        idx[q] = ii;
    }
    __syncthreads();
    size_t base = (size_t)b * 2500 * 256;
    size_t co = base + (size_t)t * 256 + q;
    float center = (bf2f(H0[co]) + bf2f(H1[co])) + bf2f(H2[co]);
    float mx = -INFINITY;
    for (int kk = 0; kk < k; kk++) {
        size_t no = base + (size_t)idx[kk] * 256 + q;
        float v = (bf2f(H0[no]) + bf2f(H1[no])) + bf2f(H2[no]);
        mx = fmaxf(mx, v - center);
    }
    unsigned pc = pack2(center), pd = pack2(mx);
    size_t fo = (size_t)b * 2500 * 256 + (size_t)t * 256 + q;  // u32 pair index
    ((unsigned*)F0)[fo] = (pc >> 16) | (pd & 0xFFFF0000u);
    ((unsigned*)F1)[fo] = (pc & 0xFFFFu) | (pd << 16);
    ((unsigned*)F2)[fo] = bf16r(center - unpk(pc)) | (bf16r(mx - unpk(pd)) << 16);
}

// ---------------------------------------------------------------------------
// Final transpose — unchanged
// ---------------------------------------------------------------------------
__global__ __launch_bounds__(256)
void outt_k(const unsigned short* __restrict__ X0, const unsigned short* __restrict__ X1,
            const unsigned short* __restrict__ X2, float* __restrict__ out)
{
    __shared__ float tile[64][65];
    int t0 = blockIdx.x * 64, c0 = blockIdx.y * 64, b = blockIdx.z;
    int tid = threadIdx.x;
    int tl = tid & 63;
#pragma unroll
    for (int p = 0; p < 16; p++) {
        int tt = (tid >> 6) + p * 4;
        int t = t0 + tt;
        int tc = (t < 2500) ? t : 2499;
        size_t off = ((size_t)b * 2500 + tc) * 256 + c0 + tl;
        tile[tl][tt] = (bf2f(X0[off]) + bf2f(X1[off])) + bf2f(X2[off]);
    }
    __syncthreads();
#pragma unroll
    for (int p = 0; p < 16; p++) {
        int cc = (tid >> 6) + p * 4;
        int t = t0 + tl;
        if (t < 2500)
            out[((size_t)b * 256 + c0 + cc) * 2500 + t] = tile[cc][tl];
    }
}

// ---------------------------------------------------------------------------
extern "C" void kernel_launch(void* const* d_in, const int* in_sizes, int n_in,
                              void* d_out, int out_size, void* d_ws, size_t ws_size,
                              hipStream_t stream)
{
    (void)in_sizes; (void)n_in; (void)out_size; (void)ws_size;
    const float* x_in = (const float*)d_in[0];
    const float *swp[5], *sbp[5], *sgp[5], *sbep[5];
    for (int i = 0; i < 5; i++) {
        swp[i] = (const float*)d_in[1 + 4 * i];
        sbp[i] = (const float*)d_in[2 + 4 * i];
        sgp[i] = (const float*)d_in[3 + 4 * i];
        sbep[i] = (const float*)d_in[4 + 4 * i];
    }
    const float* fc1_w = (const float*)d_in[21];
    const float* fc1_b = (const float*)d_in[22];
    const float* fc1_g = (const float*)d_in[23];
    const float* fc1_be = (const float*)d_in[24];
    const float* mr_w = (const float*)d_in[25];
    const float* mr_g = (const float*)d_in[26];
    const float* mr_be = (const float*)d_in[27];
    const float* fc2_w = (const float*)d_in[28];
    const float* fc2_b = (const float*)d_in[29];
    const float* fc2_g = (const float*)d_in[30];
    const float* fc2_be = (const float*)d_in[31];
    const float* ffn1_w = (const float*)d_in[32];
    const float* ffn1_b = (const float*)d_in[33];
    const float* ffn1_g = (const float*)d_in[34];
    const float* ffn1_be = (const float*)d_in[35];
    const float* ffn2_w = (const float*)d_in[36];
    const float* ffn2_b = (const float*)d_in[37];
    const float* ffn2_g = (const float*)d_in[38];
    const float* ffn2_be = (const float*)d_in[39];

    float* ws = (float*)d_ws;
    // ---- workspace layout (float units; r6-proven) ----
    const size_t NEG_F = 1920000;
    const size_t G_F   = 3840000;
    const size_t TI_F  = 3000000;      // stem-only, dead by main loop
    const size_t CW_F  = 10300000;
    const size_t X_F   = 12500000;
    const size_t HF_F  = 14420000;
    const size_t W_F   = 16340000;
    const size_t SQ_F  = 17815000;
    const size_t PART_F = 17820000;
    const size_t FIN_F = 17829000;
    const size_t IDX_F = 17830000;

    float* ping = ws;
    float* pong = ws + X_F;
    float* NEG  = ws + NEG_F;
    unsigned short* HT0 = (unsigned short*)ws;            // HTn planes
    unsigned short* HT1 = HT0 + 1280000;
    unsigned short* HT2 = HT0 + 2560000;
    unsigned short* Fp0 = (unsigned short*)ws;            // F planes
    unsigned short* Fp1 = Fp0 + 2560000;
    unsigned short* Fp2 = Fp0 + 5120000;
    unsigned short* Gp0 = (unsigned short*)(ws + G_F);    // G planes
    unsigned short* Gp1 = Gp0 + 2560000;
    unsigned short* Gp2 = Gp0 + 5120000;
    unsigned short* H20 = (unsigned short*)ws;            // HF2 planes
    unsigned short* H21 = H20 + 5120000;
    unsigned short* H22 = H20 + 10240000;
    unsigned short* TI0 = (unsigned short*)(ws + TI_F);   // stem split-T planes
    unsigned short* CW0 = (unsigned short*)(ws + CW_F);
    unsigned short* X0 = (unsigned short*)(ws + X_F);
    unsigned short* X1 = X0 + 1280000;
    unsigned short* X2 = X0 + 2560000;
    unsigned short* HF0 = (unsigned short*)(ws + HF_F);
    unsigned short* HF1 = HF0 + 1280000;
    unsigned short* HF2b = HF0 + 2560000;
    unsigned short* W0 = (unsigned short*)(ws + W_F);
    unsigned short* W1 = W0 + 983040;
    unsigned short* W2 = W0 + 1966080;
    float* SQ = ws + SQ_F;
    double* PART = (double*)(ws + PART_F);
    float* FIN = ws + FIN_F;
    int* IDX = (int*)(ws + IDX_F);

    // ---------------- stem ----------------
    int Co[5] = {32, 64, 128, 256, 256};
    int Ho[5] = {400, 200, 100, 50, 50};
    int Ssub[5] = {8, 8, 4, 2, 2};
    float* cur = nullptr;
    for (int l = 0; l < 5; l++) {
        float* outb = (l % 2 == 0) ? ping : pong;
        int HWo = Ho[l] * Ho[l];
        switch (l) {
        case 0:
            // 628 site chunks (pad from 625): S=1256, T=1256 — both %8==0
            conv3x3_t<3, 32><<<dim3(628, 1, 2), 256, 0, stream>>>(
                x_in, swp[0], sbp[0], outb, 32, 800, 800, 400, 400, 2);
            break;
        case 1:
            // 160 site chunks (pad from 157): S=320, T=640 — both %8==0
            conv3x3_t<32, 32><<<dim3(160, 2, 2), 256, 0, stream>>>(
                cur, swp[1], sbp[1], outb, 64, 400, 400, 200, 200, 2);
            break;
        case 2:
            // 40 site chunks: S=80, T=640 — both %8==0
            conv3x3_t<64, 16><<<dim3(40, 8, 2), 256, 0, stream>>>(
                cur, swp[2], sbp[2], outb, 128, 200, 200, 100, 100, 2);
            break;
        case 3: {
            int psz = 2 * 10000 * 128;
            splitT_k<<<dim3(157, 2, 2), 256, 0, stream>>>(
                cur, TI0, TI0 + psz, TI0 + 2 * psz, 128, 10000);
            int tot = 256 * 1152;
            wconvp_k<<<(tot + 255) / 256, 256, 0, stream>>>(
                swp[3], CW0, CW0 + tot, CW0 + 2 * tot, 128, tot);
            mconv6p_k<128><<<dim3(40, 4, 2), 256, 0, stream>>>(
                TI0, TI0 + psz, TI0 + 2 * psz, CW0, CW0 + tot, CW0 + 2 * tot,
                sbp[3], outb, 256, 100, 100, 50, 50, 2);
            break;
        }
        case 4: {
            int psz = 2 * 2500 * 256;
            splitT_k<<<dim3(40, 4, 2), 256, 0, stream>>>(
                cur, TI0, TI0 + psz, TI0 + 2 * psz, 256, 2500);
            int tot = 256 * 2304;
            wconvp_k<<<(tot + 255) / 256, 256, 0, stream>>>(
                swp[4], CW0, CW0 + tot, CW0 + 2 * tot, 256, tot);
            mconv6p_k<256><<<dim3(40, 4, 2), 256, 0, stream>>>(
                TI0, TI0 + psz, TI0 + 2 * psz, CW0, CW0 + tot, CW0 + 2 * tot,
                sbp[4], outb, 256, 50, 50, 50, 50, 1);
            break;
        }
        }
        int cpg = Co[l] / 32;
        gn_stats_k<<<dim3(Ssub[l], 32, 2), 256, 0, stream>>>(outb, PART, Co[l], HWo, cpg, Ssub[l]);
        gn_reduce_k<<<1, 64, 0, stream>>>(PART, FIN, Ssub[l], (double)cpg * (double)HWo);
        int total = 2 * Co[l] * HWo;
        gn_apply_k<<<(total + 255) / 256, 256, 0, stream>>>(outb, FIN, sgp[l], sbep[l],
                                                            Co[l], HWo, cpg, (l < 4) ? 1 : 0, total);
        cur = outb;
    }
    posadd_k<<<dim3(40, 4, 2), 256, 0, stream>>>(cur, X0, X1, X2);

    // ---------------- 12 Grapher + FFN blocks ----------------
    const int KS[12] = {9, 9, 10, 11, 12, 13, 13, 14, 15, 16, 17, 18};
    const int DILS[12] = {1, 1, 1, 1, 2, 2, 2, 2, 3, 3, 3, 3};
    const int D = 256, N = 2500;

    for (int i = 0; i < 12; i++) {
        pack5p_k<<<3840, 256, 0, stream>>>(
            fc1_w + (size_t)i * 65536, mr_w + (size_t)i * 262144,
            fc2_w + (size_t)i * 131072, ffn1_w + (size_t)i * 262144,
            ffn2_w + (size_t)i * 262144, W0, W1, W2);

        // fc1 -> HF planes
        mgemm6p_k<2><<<dim3(40, 4, 2), 256, 0, stream>>>(
            X0, X1, X2, W0, W1, W2,
            fc1_b + i * D, fc1_g + i * D, fc1_be + i * D,
            nullptr, nullptr, nullptr, HF0, HF1, HF2b, N, D, D, 0);
        tok_k<<<dim3(625, 2), 256, 0, stream>>>(HF0, HF1, HF2b, HT0, HT1, HT2, SQ);
        for (int bz = 0; bz < 2; bz++) {
            mdist6p_k<<<dim3(820, 1, 1), 256, 0, stream>>>(HT0, HT1, HT2, SQ, NEG, N, D, bz);
            topk_k<<<dim3(1250, 1, 1), 128, 0, stream>>>(NEG, IDX, N,
                                                         KS[i] * DILS[i], DILS[i], KS[i], bz);
        }
        gather_k<<<dim3(2500, 2), 256, 0, stream>>>(HF0, HF1, HF2b, IDX, Fp0, Fp1, Fp2, KS[i]);
        // mr -> G planes
        mgemm6p_k<4><<<dim3(40, 4, 2), 256, 0, stream>>>(
            Fp0, Fp1, Fp2, W0 + 65536, W1 + 65536, W2 + 65536,
            nullptr, mr_g + i * 512, mr_be + i * 512,
            nullptr, nullptr, nullptr, Gp0, Gp1, Gp2, N, 512, 512, 1);
        // fc2 + residual -> X planes
        mgemm6p_k<2><<<dim3(40, 4, 2), 256, 0, stream>>>(
            Gp0, Gp1, Gp2, W0 + 327680, W1 + 327680, W2 + 327680,
            fc2_b + i * D, fc2_g + i * D, fc2_be + i * D,
            X0, X1, X2, X0, X1, X2, N, D, 512, 0);
        // ffn1 -> HF2 planes
        mgemm6p_k<4><<<dim3(40, 8, 2), 256, 0, stream>>>(
            X0, X1, X2, W0 + 458752, W1 + 458752, W2 + 458752,
            ffn1_b + i * 1024, ffn1_g + i * 1024, ffn1_be + i * 1024,
            nullptr, nullptr, nullptr, H20, H21, H22, N, 1024, D, 1);
        // ffn2 + residual -> X planes
        mgemm6p_k<2><<<dim3(40, 4, 2), 256, 0, stream>>>(
            H20, H21, H22, W0 + 720896, W1 + 720896, W2 + 720896,
            ffn2_b + i * D, ffn2_g + i * D, ffn2_be + i * D,
            X0, X1, X2, X0, X1, X2, N, D, 1024, 0);
    }

    outt_k<<<dim3(40, 4, 2), 256, 0, stream>>>(X0, X1, X2, (float*)d_out);
}

// Round 14
// 3671.862 us; speedup vs baseline: 1.2559x; 1.1955x over previous
//
#include <hip/hip_runtime.h>
#include <math.h>

#define DEVI static __device__ __forceinline__

typedef __attribute__((ext_vector_type(8))) _Float16 half8;  // 8 fp16 (4 VGPR)
typedef __attribute__((ext_vector_type(4))) float f32x4;

DEVI float gelu_f(float x) { return 0.5f * x * (1.0f + erff(x * 0.70710678118654752440f)); }

// ---- 2-split fp16: x ~= h0 + h1 (each RN fp16); storage = 2 planes.
// |x-h0-h1| <= 2^-22|x|; 3-term product error ~2^-22 (drops h1*w1 only).
DEVI unsigned short f2h(float x)
{
    _Float16 h = (_Float16)x;
    unsigned short u; __builtin_memcpy(&u, &h, 2); return u;
}
DEVI float h2f(unsigned short u)
{
    _Float16 h; __builtin_memcpy(&h, &u, 2); return (float)h;
}

// LDS plane row: 32 fp16 = 16 data u32 + 2 pad = 18 u32 stride (proven r4).
DEVI half8 ldfh(const unsigned* P, int row, int kq)
{
    const unsigned* b = P + row * 18 + kq * 2;
    union { uint2 h[2]; half8 s; } r;
    r.h[0] = *(const uint2*)(b);
    r.h[1] = *(const uint2*)(b + 8);
    return r.s;
}
DEVI void st4(unsigned* b, uint4 v0)
{
    uint2 t;
    t.x = v0.x; t.y = v0.y; *(uint2*)(b) = t;
    t.x = v0.z; t.y = v0.w; *(uint2*)(b + 2) = t;
}
DEVI void st8(unsigned* b, uint4 v0, uint4 v1)
{
    uint2 t;
    t.x = v0.x; t.y = v0.y; *(uint2*)(b) = t;
    t.x = v0.z; t.y = v0.w; *(uint2*)(b + 2) = t;
    t.x = v1.x; t.y = v1.y; *(uint2*)(b + 4) = t;
    t.x = v1.z; t.y = v1.w; *(uint2*)(b + 6) = t;
}

#define MFMA3(ACC, A0, A1, W0, W1) do { \
    ACC = __builtin_amdgcn_mfma_f32_16x16x32_f16(A1, W0, ACC, 0, 0, 0); \
    ACC = __builtin_amdgcn_mfma_f32_16x16x32_f16(A0, W1, ACC, 0, 0, 0); \
    ACC = __builtin_amdgcn_mfma_f32_16x16x32_f16(A0, W0, ACC, 0, 0, 0); \
} while (0)

// ---------------------------------------------------------------------------
// Direct 3x3 conv for small Cin (stem L0-L2) — r13 XCD-swizzled (proven)
// ---------------------------------------------------------------------------
template <int CIN, int NCO>
__global__ __launch_bounds__(256)
void conv3x3_t(const float* __restrict__ in, const float* __restrict__ w,
               const float* __restrict__ bias, float* __restrict__ out,
               int Cout, int Hin, int Win, int Hout, int Wout, int stride)
{
    __shared__ __align__(16) float wlds[CIN * 9 * NCO];
    int nsx = gridDim.x, nco = gridDim.y;
    int fid = blockIdx.x + nsx * (blockIdx.y + nco * blockIdx.z);
    int S = nsx * gridDim.z;
    int sPer = S >> 3;
    int k8 = fid & 7, j = fid >> 3;
    int site_inst = k8 + 8 * (j % sPer);
    int co_g = j / sPer;
    int sx = site_inst % nsx;
    int b = site_inst / nsx;

    int co0 = co_g * NCO;
    int tid = threadIdx.x;
    int HWo = Hout * Wout;
    int s = sx * 256 + tid;
    int sc = (s < HWo) ? s : (HWo - 1);
    int ho = sc / Wout, wo = sc % Wout;
    float acc[NCO];
#pragma unroll
    for (int jj = 0; jj < NCO; jj++) acc[jj] = bias[co0 + jj];
    const float* inb = in + (size_t)b * CIN * Hin * Win;
    size_t HWi = (size_t)Hin * Win;

    const int nw = NCO * CIN * 9;
    for (int i = tid; i < nw; i += 256) {
        int jj = i % NCO;
        int rest = i / NCO;
        int ci = rest % CIN, tap = rest / CIN;
        wlds[i] = w[((size_t)(co0 + jj) * CIN + ci) * 9 + tap];
    }
    __syncthreads();
    for (int kh = 0; kh < 3; kh++) {
        int hi = ho * stride - 1 + kh;
        bool okh = (hi >= 0 && hi < Hin);
        for (int kw = 0; kw < 3; kw++) {
            int wi = wo * stride - 1 + kw;
            if (!okh || wi < 0 || wi >= Win) continue;
            int tap = kh * 3 + kw;
            const float* ip = inb + (size_t)hi * Win + wi;
            const float* wp = wlds + (size_t)tap * CIN * NCO;
#pragma unroll 4
            for (int ci = 0; ci < CIN; ci++) {
                float xv = ip[(size_t)ci * HWi];
                const float* wq = wp + ci * NCO;
#pragma unroll
                for (int j4 = 0; j4 < NCO; j4 += 4) {
                    float4 wv = *(const float4*)(wq + j4);
                    acc[j4 + 0] += xv * wv.x; acc[j4 + 1] += xv * wv.y;
                    acc[j4 + 2] += xv * wv.z; acc[j4 + 3] += xv * wv.w;
                }
            }
        }
    }
    if (s < HWo) {
        size_t ob = ((size_t)b * Cout + co0) * HWo + s;
#pragma unroll
        for (int jj = 0; jj < NCO; jj++) out[ob + (size_t)jj * HWo] = acc[jj];
    }
}

// ---------------------------------------------------------------------------
// GroupNorm (deterministic) — unchanged
// ---------------------------------------------------------------------------
__global__ __launch_bounds__(256)
void gn_stats_k(const float* __restrict__ x, double* __restrict__ part,
                int C, int HW, int cpg, int S)
{
    int srt = blockIdx.x, g = blockIdx.y, b = blockIdx.z;
    long len = (long)cpg * HW;
    long chunk = (len + S - 1) / S;
    long lo = (long)srt * chunk;
    long hi = lo + chunk; if (hi > len) hi = len;
    const float* xp = x + ((size_t)b * C + (size_t)g * cpg) * HW;
    double s1 = 0.0, s2 = 0.0;
    for (long i = lo + threadIdx.x; i < hi; i += 256) {
        double v = (double)xp[i];
        s1 += v; s2 += v * v;
    }
    __shared__ double r1[256], r2[256];
    r1[threadIdx.x] = s1; r2[threadIdx.x] = s2;
    __syncthreads();
    for (int t = 128; t > 0; t >>= 1) {
        if (threadIdx.x < t) { r1[threadIdx.x] += r1[threadIdx.x + t]; r2[threadIdx.x] += r2[threadIdx.x + t]; }
        __syncthreads();
    }
    if (threadIdx.x == 0) {
        size_t slot = ((size_t)(b * 32 + g) * S + srt) * 2;
        part[slot] = r1[0];
        part[slot + 1] = r2[0];
    }
}

__global__ __launch_bounds__(64)
void gn_reduce_k(const double* __restrict__ part, float* __restrict__ fin,
                 int S, double cnt)
{
    int t = threadIdx.x;
    double s1 = 0.0, s2 = 0.0;
    for (int s = 0; s < S; s++) {
        size_t slot = ((size_t)t * S + s) * 2;
        s1 += part[slot];
        s2 += part[slot + 1];
    }
    double m = s1 / cnt;
    double var = s2 / cnt - m * m;
    double inv = 1.0 / sqrt(var + 1e-5);
    fin[t * 2] = (float)m;
    fin[t * 2 + 1] = (float)inv;
}

__global__ __launch_bounds__(256)
void gn_apply_k(float* __restrict__ x, const float* __restrict__ fin,
                const float* __restrict__ gma, const float* __restrict__ bta,
                int C, int HW, int cpg, int do_gelu, int total)
{
    int idx = blockIdx.x * 256 + threadIdx.x;
    if (idx >= total) return;
    int c = (idx / HW) % C;
    int b = idx / (HW * C);
    int g = c / cpg;
    float m = fin[(b * 32 + g) * 2];
    float inv = fin[(b * 32 + g) * 2 + 1];
    float v = (x[idx] - m) * inv * gma[c] + bta[c];
    if (do_gelu) v = gelu_f(v);
    x[idx] = v;
}

// ---------------------------------------------------------------------------
// Transpose+split stem input: in[b][c][hw] fp32 -> 2 planes [b][hw][c] fp16
// ---------------------------------------------------------------------------
__global__ __launch_bounds__(256)
void splitT_k(const float* __restrict__ in, unsigned short* __restrict__ P0,
              unsigned short* __restrict__ P1, int C, int HW)
{
    __shared__ float tile[64][65];
    int h0 = blockIdx.x * 64, c0 = blockIdx.y * 64, b = blockIdx.z;
    int tid = threadIdx.x;
    int tl = tid & 63;
    const float* inb = in + (size_t)b * C * HW;
#pragma unroll
    for (int p = 0; p < 16; p++) {
        int c = (tid >> 6) + p * 4;
        int h = h0 + tl;
        tile[c][tl] = (h < HW) ? inb[(size_t)(c0 + c) * HW + h] : 0.f;
    }
    __syncthreads();
#pragma unroll
    for (int p = 0; p < 16; p++) {
        int hh = (tid >> 6) + p * 4;
        int h = h0 + hh;
        if (h >= HW) continue;
        int ch = c0 + tl;
        float v = tile[tl][hh];
        unsigned short a = f2h(v);
        size_t off = ((size_t)b * HW + h) * C + ch;
        P0[off] = a;
        P1[off] = f2h(v - h2f(a));
    }
}

// ---------------------------------------------------------------------------
// Conv weight pack to 2 planes, k = tap*Cin + ci
// ---------------------------------------------------------------------------
__global__ __launch_bounds__(256)
void wconvp_k(const float* __restrict__ w, unsigned short* __restrict__ P0,
              unsigned short* __restrict__ P1, int Cin, int total)
{
    int idx = blockIdx.x * 256 + threadIdx.x;
    if (idx >= total) return;
    int K = Cin * 9;
    int co = idx / K, k = idx % K;
    int tap = k / Cin, ci = k - tap * Cin;
    float v = w[((size_t)co * Cin + ci) * 9 + tap];
    unsigned short a = f2h(v);
    P0[idx] = a;
    P1[idx] = f2h(v - h2f(a));
}

// ---------------------------------------------------------------------------
// Main-loop weight pack (fc1|mr|fc2|ffn1|ffn2) to 2 planes
// ---------------------------------------------------------------------------
__global__ __launch_bounds__(256)
void pack5p_k(const float* __restrict__ s0, const float* __restrict__ s1,
              const float* __restrict__ s2, const float* __restrict__ s3,
              const float* __restrict__ s4, unsigned short* __restrict__ P0,
              unsigned short* __restrict__ P1)
{
    int idx = blockIdx.x * 256 + threadIdx.x;   // grid exact: 983040
    float v;
    if (idx < 65536)       v = s0[idx];
    else if (idx < 327680) v = s1[idx - 65536];
    else if (idx < 458752) v = s2[idx - 327680];
    else if (idx < 720896) v = s3[idx - 458752];
    else                   v = s4[idx - 720896];
    unsigned short a = f2h(v);
    P0[idx] = a;
    P1[idx] = f2h(v - h2f(a));
}

// ---------------------------------------------------------------------------
// MFMA GEMM, 3-term fp16 2-split, r10-proven structure: BN=64, single LDS
// buffer, issue-early register prefetch, occ-3.
// ---------------------------------------------------------------------------
template <int JT>
__global__ __launch_bounds__(256, 3)
void mgemm3h_k(const unsigned short* __restrict__ A0, const unsigned short* __restrict__ A1,
               const unsigned short* __restrict__ W0, const unsigned short* __restrict__ W1,
               const float* __restrict__ bias, const float* __restrict__ gma,
               const float* __restrict__ bta,
               const unsigned short* __restrict__ R0, const unsigned short* __restrict__ R1,
               unsigned short* __restrict__ C0, unsigned short* __restrict__ C1,
               int N, int M, int K, int do_gelu)
{
    const int BM = 32 * JT;
    __shared__ __align__(16) unsigned lA[2][64 * 18];
    __shared__ __align__(16) unsigned lW[2][BM * 18];
    int bz = blockIdx.z;
    int n0 = blockIdx.x * 64, m0 = blockIdx.y * BM;
    int tid = threadIdx.x, wave = tid >> 6, lane = tid & 63;
    int wn = (wave & 1) * 32, wm = (wave >> 1) * (16 * JT);
    int rl = lane & 15, kq = lane >> 4;

    f32x4 acc[2][JT] = {};

    const unsigned* Ag[2] = {(const unsigned*)A0, (const unsigned*)A1};
    const unsigned* Wg[2] = {(const unsigned*)W0, (const unsigned*)W1};

    int ar = tid >> 2, ah = tid & 3;
    int aga = n0 + ar; if (aga >= N) aga = N - 1;
    size_t abase = (((size_t)bz * N + aga) * K) >> 1;
    unsigned* sA[2];
#pragma unroll
    for (int pl = 0; pl < 2; pl++) sA[pl] = &lA[pl][ar * 18 + ah * 4];

    int wr_ = (JT == 4) ? (tid >> 1) : (tid >> 2);
    int wo_ = (JT == 4) ? ((tid & 1) * 8) : ((tid & 3) * 4);
    size_t wbase = ((size_t)(m0 + wr_) * K) >> 1;
    unsigned* sW[2];
#pragma unroll
    for (int pl = 0; pl < 2; pl++) sW[pl] = &lW[pl][wr_ * 18 + wo_];

    uint4 pa[2], pw[2][2];

#pragma unroll
    for (int pl = 0; pl < 2; pl++) {
        pa[pl] = *(const uint4*)(Ag[pl] + abase + ah * 4);
        const unsigned* h = Wg[pl] + wbase + wo_;
        pw[pl][0] = *(const uint4*)(h);
        if (JT == 4) pw[pl][1] = *(const uint4*)(h + 4);
    }
#pragma unroll
    for (int pl = 0; pl < 2; pl++) {
        st4(sA[pl], pa[pl]);
        if (JT == 4) st8(sW[pl], pw[pl][0], pw[pl][1]); else st4(sW[pl], pw[pl][0]);
    }
    __syncthreads();

    for (int k0 = 0; k0 < K; k0 += 32) {
        bool more = (k0 + 32) < K;
        if (more) {
#pragma unroll
            for (int pl = 0; pl < 2; pl++) {
                pa[pl] = *(const uint4*)(Ag[pl] + abase + ((k0 + 32) >> 1) + ah * 4);
                const unsigned* h = Wg[pl] + wbase + ((k0 + 32) >> 1) + wo_;
                pw[pl][0] = *(const uint4*)(h);
                if (JT == 4) pw[pl][1] = *(const uint4*)(h + 4);
            }
        }
        half8 a0[2], a1[2];
#pragma unroll
        for (int i = 0; i < 2; i++) {
            int ra = wn + i * 16 + rl;
            a0[i] = ldfh(lA[0], ra, kq);
            a1[i] = ldfh(lA[1], ra, kq);
        }
        half8 w0[JT], w1[JT];
#pragma unroll
        for (int j = 0; j < JT; j++) {
            int rw = wm + j * 16 + rl;
            w0[j] = ldfh(lW[0], rw, kq);
            w1[j] = ldfh(lW[1], rw, kq);
        }
#pragma unroll
        for (int i = 0; i < 2; i++) {
#pragma unroll
            for (int j = 0; j < JT; j++) {
                MFMA3(acc[i][j], a0[i], a1[i], w0[j], w1[j]);
            }
        }
        __syncthreads();
        if (more) {
#pragma unroll
            for (int pl = 0; pl < 2; pl++) {
                st4(sA[pl], pa[pl]);
                if (JT == 4) st8(sW[pl], pw[pl][0], pw[pl][1]); else st4(sW[pl], pw[pl][0]);
            }
            __syncthreads();
        }
    }

#pragma unroll
    for (int j = 0; j < JT; j++) {
        int mm = m0 + wm + j * 16 + rl;
        float bs = bias ? bias[mm] : 0.f;
        float gm = gma[mm], bt = bta[mm];
#pragma unroll
        for (int i = 0; i < 2; i++) {
            int tn = n0 + wn + i * 16 + kq * 4;
            f32x4 a = acc[i][j];
#pragma unroll
            for (int r = 0; r < 4; r++) {
                int gn2 = tn + r;
                if (gn2 >= N) continue;
                float v = (a[r] + bs) * gm + bt;
                if (do_gelu) v = gelu_f(v);
                size_t off = ((size_t)bz * N + gn2) * M + mm;
                if (R0) v += h2f(R0[off]) + h2f(R1[off]);
                unsigned short c0 = f2h(v);
                C0[off] = c0;
                C1[off] = f2h(v - h2f(c0));
            }
        }
    }
}

// ---------------------------------------------------------------------------
// MFMA distance syrk, 3-term fp16 2-split, upper-tri + mirror, 64x64 occ-3.
// ---------------------------------------------------------------------------
__global__ __launch_bounds__(256, 3)
void mdist3h_k(const unsigned short* __restrict__ H0, const unsigned short* __restrict__ H1,
               const float* __restrict__ SQ, float* __restrict__ NEG,
               int Nn, int K, int bz)
{
    __shared__ __align__(16) unsigned lA[2][64 * 18];
    __shared__ __align__(16) unsigned lW[2][64 * 18];
    int q = blockIdx.x;
    int ti = 0;
    while (q >= 40 - ti) { q -= 40 - ti; ti++; }
    int tj = ti + q;
    int i0 = ti * 64, j0 = tj * 64;
    int tid = threadIdx.x, wave = tid >> 6, lane = tid & 63;
    int wn = (wave & 1) * 32, wm = (wave >> 1) * 32;
    int rl = lane & 15, kq = lane >> 4;

    f32x4 acc[2][2] = {};

    const unsigned* Hg[2] = {(const unsigned*)H0, (const unsigned*)H1};

    int ar = tid >> 2, ah = tid & 3;
    int gi = i0 + ar; if (gi >= Nn) gi = Nn - 1;
    int gj = j0 + ar; if (gj >= Nn) gj = Nn - 1;
    size_t ibase = (((size_t)bz * Nn + gi) * K) >> 1;
    size_t jbase = (((size_t)bz * Nn + gj) * K) >> 1;
    unsigned* sA[2];
    unsigned* sW[2];
#pragma unroll
    for (int pl = 0; pl < 2; pl++) {
        sA[pl] = &lA[pl][ar * 18 + ah * 4];
        sW[pl] = &lW[pl][ar * 18 + ah * 4];
    }

    uint4 pa[2], pj[2];
#pragma unroll
    for (int pl = 0; pl < 2; pl++) {
        pa[pl] = *(const uint4*)(Hg[pl] + ibase + ah * 4);
        pj[pl] = *(const uint4*)(Hg[pl] + jbase + ah * 4);
    }
#pragma unroll
    for (int pl = 0; pl < 2; pl++) {
        st4(sA[pl], pa[pl]);
        st4(sW[pl], pj[pl]);
    }
    __syncthreads();

    for (int k0 = 0; k0 < K; k0 += 32) {
        bool more = (k0 + 32) < K;
        if (more) {
#pragma unroll
            for (int pl = 0; pl < 2; pl++) {
                pa[pl] = *(const uint4*)(Hg[pl] + ibase + ((k0 + 32) >> 1) + ah * 4);
                pj[pl] = *(const uint4*)(Hg[pl] + jbase + ((k0 + 32) >> 1) + ah * 4);
            }
        }
        half8 a0[2], a1[2], w0[2], w1[2];
#pragma unroll
        for (int i = 0; i < 2; i++) {
            int ra = wn + i * 16 + rl;
            a0[i] = ldfh(lA[0], ra, kq);
            a1[i] = ldfh(lA[1], ra, kq);
            int rw = wm + i * 16 + rl;
            w0[i] = ldfh(lW[0], rw, kq);
            w1[i] = ldfh(lW[1], rw, kq);
        }
#pragma unroll
        for (int i = 0; i < 2; i++) {
#pragma unroll
            for (int j = 0; j < 2; j++) {
                MFMA3(acc[i][j], a0[i], a1[i], w0[j], w1[j]);
            }
        }
        __syncthreads();
        if (more) {
#pragma unroll
            for (int pl = 0; pl < 2; pl++) {
                st4(sA[pl], pa[pl]);
                st4(sW[pl], pj[pl]);
            }
            __syncthreads();
        }
    }

    const float* SQb = SQ + (size_t)bz * Nn;
#pragma unroll
    for (int j = 0; j < 2; j++) {
        int nj = j0 + wm + j * 16 + rl;
        if (nj >= Nn) continue;
        float sj = SQb[nj];
#pragma unroll
        for (int i = 0; i < 2; i++) {
            int nio = i0 + wn + i * 16 + kq * 4;
            f32x4 a = acc[i][j];
#pragma unroll
            for (int r = 0; r < 4; r++) {
                int ni = nio + r;
                if (ni >= Nn) continue;
                float d = 2.f * a[r] - SQb[ni] - sj;
                NEG[(size_t)ni * Nn + nj] = d;
                if (i0 != j0) NEG[(size_t)nj * Nn + ni] = d;
            }
        }
    }
}

// ---------------------------------------------------------------------------
// MFMA implicit-im2col 3x3 conv (stem L3/L4), 3-term fp16, BN=64 occ-3.
// ---------------------------------------------------------------------------
template <int CIN>
__global__ __launch_bounds__(256, 3)
void mconv3h_k(const unsigned short* __restrict__ T0, const unsigned short* __restrict__ T1,
               const unsigned short* __restrict__ Wc0, const unsigned short* __restrict__ Wc1,
               const float* __restrict__ bias, float* __restrict__ out,
               int Cout, int Hin, int Win, int Hout, int Wout, int stride)
{
    const int K = 9 * CIN;
    __shared__ __align__(16) unsigned lA[2][64 * 18];
    __shared__ __align__(16) unsigned lW[2][64 * 18];
    int bz = blockIdx.z;
    int n0 = blockIdx.x * 64, m0 = blockIdx.y * 64;
    int HWo = Hout * Wout;
    int tid = threadIdx.x, wave = tid >> 6, lane = tid & 63;
    int wn = (wave & 1) * 32, wm = (wave >> 1) * 32;
    int rl = lane & 15, kq = lane >> 4;

    f32x4 acc[2][2] = {};

    const unsigned* Tg[2] = {(const unsigned*)T0, (const unsigned*)T1};
    const unsigned* Wg[2] = {(const unsigned*)Wc0, (const unsigned*)Wc1};

    int ar = tid >> 2, ah = tid & 3;
    int s = n0 + ar; if (s >= HWo) s = HWo - 1;
    int ho = s / Wout, wo = s % Wout;
    unsigned* sA[2];
#pragma unroll
    for (int pl = 0; pl < 2; pl++) sA[pl] = &lA[pl][ar * 18 + ah * 4];

    int wr_ = tid >> 2, wo_ = (tid & 3) * 4;
    size_t wbase = ((size_t)(m0 + wr_) * K) >> 1;
    unsigned* sW[2];
#pragma unroll
    for (int pl = 0; pl < 2; pl++) sW[pl] = &lW[pl][wr_ * 18 + wo_];
    size_t HWi = (size_t)Hin * Win;

    uint4 pa[2], pw[2];

    auto loadS = [&](int ks) {
        int kk = ks * 32;
        int tap = kk / CIN;
        int kh = tap / 3, kw = tap % 3;
        int hi = ho * stride - 1 + kh;
        int wi = wo * stride - 1 + kw;
        bool ok = (hi >= 0 && hi < Hin && wi >= 0 && wi < Win);
        if (ok) {
            size_t base = (((size_t)bz * HWi + (size_t)(hi * Win + wi)) * CIN + (kk % CIN)) >> 1;
#pragma unroll
            for (int pl = 0; pl < 2; pl++)
                pa[pl] = *(const uint4*)(Tg[pl] + base + ah * 4);
        } else {
            uint4 z; z.x = 0; z.y = 0; z.z = 0; z.w = 0;
#pragma unroll
            for (int pl = 0; pl < 2; pl++) pa[pl] = z;
        }
#pragma unroll
        for (int pl = 0; pl < 2; pl++)
            pw[pl] = *(const uint4*)(Wg[pl] + wbase + ks * 16 + wo_);
    };
    auto stS = [&]() {
#pragma unroll
        for (int pl = 0; pl < 2; pl++) {
            st4(sA[pl], pa[pl]);
            st4(sW[pl], pw[pl]);
        }
    };

    int nst = K >> 5;
    loadS(0);
    stS();
    __syncthreads();

    for (int ks = 0; ks < nst; ks++) {
        bool more = (ks + 1) < nst;
        if (more) loadS(ks + 1);
        half8 a0[2], a1[2];
#pragma unroll
        for (int i = 0; i < 2; i++) {
            int ra = wn + i * 16 + rl;
            a0[i] = ldfh(lA[0], ra, kq);
            a1[i] = ldfh(lA[1], ra, kq);
        }
        half8 w0[2], w1[2];
#pragma unroll
        for (int j = 0; j < 2; j++) {
            int rw = wm + j * 16 + rl;
            w0[j] = ldfh(lW[0], rw, kq);
            w1[j] = ldfh(lW[1], rw, kq);
        }
#pragma unroll
        for (int i = 0; i < 2; i++) {
#pragma unroll
            for (int j = 0; j < 2; j++) {
                MFMA3(acc[i][j], a0[i], a1[i], w0[j], w1[j]);
            }
        }
        __syncthreads();
        if (more) {
            stS();
            __syncthreads();
        }
    }

#pragma unroll
    for (int j = 0; j < 2; j++) {
        int mm = m0 + wm + j * 16 + rl;
        float bs = bias[mm];
#pragma unroll
        for (int i = 0; i < 2; i++) {
            int tn = n0 + wn + i * 16 + kq * 4;
            f32x4 a = acc[i][j];
#pragma unroll
            for (int r = 0; r < 4; r++) {
                int gn2 = tn + r;
                if (gn2 < HWo)
                    out[((size_t)bz * Cout + mm) * HWo + gn2] = a[r] + bs;
            }
        }
    }
}

// ---------------------------------------------------------------------------
// posadd + transpose: X planes [b][t][c] = split(x[b][c][t] + pos)
// ---------------------------------------------------------------------------
__global__ __launch_bounds__(256)
void posadd_k(const float* __restrict__ xin, unsigned short* __restrict__ X0,
              unsigned short* __restrict__ X1)
{
    __shared__ float tile[64][65];
    int t0 = blockIdx.x * 64, c0 = blockIdx.y * 64, b = blockIdx.z;
    int tid = threadIdx.x;
    int tl = tid & 63;
    const float* inb = xin + (size_t)b * 256 * 2500;
#pragma unroll
    for (int p = 0; p < 16; p++) {
        int c = (tid >> 6) + p * 4;
        int t = t0 + tl;
        tile[c][tl] = (t < 2500) ? inb[(size_t)(c0 + c) * 2500 + t] : 0.f;
    }
    __syncthreads();
#pragma unroll
    for (int p = 0; p < 16; p++) {
        int tt = (tid >> 6) + p * 4;
        int t = t0 + tt;
        if (t >= 2500) continue;
        int ch = c0 + tl;
        int yy = t / 50, xx = t % 50;
        int cc = ch & 127;
        double v = (double)((ch < 128) ? (yy + 1) : (xx + 1));
        v = v * (6.283185307179586476925287 / 50.0);
        double e = (double)(2 * (cc >> 1)) / 128.0;
        double d = pow(10000.0, e);
        double a = v / d;
        double pp = (cc & 1) ? cos(a) : sin(a);
        float val = tile[tl][tt] + (float)pp;
        size_t off = ((size_t)b * 2500 + t) * 256 + ch;
        unsigned short a0 = f2h(val);
        X0[off] = a0;
        X1[off] = f2h(val - h2f(a0));
    }
}

// ---------------------------------------------------------------------------
// Per-token normalize (double accumulation): HT planes, SQ. 1 wave/token.
// ---------------------------------------------------------------------------
__global__ __launch_bounds__(256)
void tok_k(const unsigned short* __restrict__ H0, const unsigned short* __restrict__ H1,
           unsigned short* __restrict__ T0, unsigned short* __restrict__ T1,
           float* __restrict__ SQ)
{
    int wave = threadIdx.x >> 6, lane = threadIdx.x & 63;
    int t = blockIdx.x * 4 + wave;
    int b = blockIdx.y;
    size_t base = ((size_t)b * 2500 + t) * 128;   // u32 pair index
    const unsigned* h0 = (const unsigned*)H0 + base;
    const unsigned* h1 = (const unsigned*)H1 + base;
    float v[4];
    double s = 0.0;
#pragma unroll
    for (int g = 0; g < 2; g++) {
        unsigned ua = h0[lane + g * 64], ub = h1[lane + g * 64];
        float lo = h2f((unsigned short)(ua & 0xFFFFu)) + h2f((unsigned short)(ub & 0xFFFFu));
        float hi = h2f((unsigned short)(ua >> 16)) + h2f((unsigned short)(ub >> 16));
        v[2 * g] = lo; v[2 * g + 1] = hi;
        s += (double)lo * lo + (double)hi * hi;
    }
#pragma unroll
    for (int off = 32; off > 0; off >>= 1) s += __shfl_xor(s, off);
    float r = (float)(1.0 / sqrt(s + 1e-12));
    unsigned* t0 = (unsigned*)T0 + base;
    unsigned* t1 = (unsigned*)T1 + base;
    double s2 = 0.0;
#pragma unroll
    for (int g = 0; g < 2; g++) {
        float x0 = v[2 * g] * r, x1 = v[2 * g + 1] * r;
        s2 += (double)x0 * x0 + (double)x1 * x1;
        unsigned short a0 = f2h(x0), b0 = f2h(x1);
        unsigned short a1 = f2h(x0 - h2f(a0)), b1 = f2h(x1 - h2f(b0));
        t0[lane + g * 64] = (unsigned)a0 | ((unsigned)b0 << 16);
        t1[lane + g * 64] = (unsigned)a1 | ((unsigned)b1 << 16);
    }
#pragma unroll
    for (int off = 32; off > 0; off >>= 1) s2 += __shfl_xor(s2, off);
    if (lane == 0) SQ[b * 2500 + t] = (float)s2;
}

// ---------------------------------------------------------------------------
// top-(k*dil): one wave per row — unchanged
// ---------------------------------------------------------------------------
DEVI unsigned long long pack_key(float x, unsigned idx)
{
    unsigned u = __float_as_uint(x);
    u = (u & 0x80000000u) ? ~u : (u | 0x80000000u);
    return ((unsigned long long)u << 32) | (unsigned long long)(0xFFFFFFFFu - idx);
}

__global__ __launch_bounds__(128)
void topk_k(const float* __restrict__ NEGc, int* __restrict__ IDX,
            int rows, int kd, int dil, int kout, int bz)
{
    __shared__ float vals[2][2560];
    int wave = threadIdx.x >> 6;
    int lane = threadIdx.x & 63;
    int i = blockIdx.x * 2 + wave;
    if (i >= rows) return;
    const float* row = NEGc + (size_t)i * 2500;
    float* v = vals[wave];
    for (int j = lane; j < 2560; j += 64)
        v[j] = (j < 2500) ? (row[j] + 0.0f) : -INFINITY;
    unsigned long long key = pack_key(-INFINITY, 0xFFFFFFFFu);
    for (int q = 0; q < 40; q++) {
        int pos = lane * 40 + q;
        unsigned long long k2 = pack_key(v[pos], (unsigned)pos);
        if (k2 > key) key = k2;
    }
    for (int t = 0; t < kd; t++) {
        unsigned long long r = key;
#pragma unroll
        for (int off = 32; off > 0; off >>= 1) {
            unsigned long long o = __shfl_xor(r, off);
            if (o > r) r = o;
        }
        int sel = (int)(0xFFFFFFFFu - (unsigned)(r & 0xFFFFFFFFull));
        if ((unsigned)sel >= 2500u) sel = 0;
        if (lane == 0 && t % dil == 0)
            IDX[(size_t)(bz * 2500 + i) * kout + t / dil] = sel;
        int lo = sel / 40;
        if (lane == lo) v[sel] = -INFINITY;
        int pos = lo * 40 + lane;
        float x = (lane < 40) ? v[pos] : -INFINITY;
        unsigned long long k2 = pack_key(x, (lane < 40) ? (unsigned)pos : 0xFFFFFFFFu);
#pragma unroll
        for (int off = 32; off > 0; off >>= 1) {
            unsigned long long o = __shfl_xor(k2, off);
            if (o > k2) k2 = o;
        }
        if (lane == lo) key = k2;
    }
}

// ---------------------------------------------------------------------------
// Gather neighbors; HF planes in, F planes out (channel-interleaved 512)
// ---------------------------------------------------------------------------
__global__ __launch_bounds__(256)
void gather_k(const unsigned short* __restrict__ H0, const unsigned short* __restrict__ H1,
              const int* __restrict__ IDX,
              unsigned short* __restrict__ F0, unsigned short* __restrict__ F1, int k)
{
    int t = blockIdx.x;
    int b = blockIdx.y;
    int q = threadIdx.x;
    __shared__ int idx[18];
    if (q < k) {
        int ii = IDX[((size_t)b * 2500 + t) * k + q];
        if ((unsigned)ii >= 2500u) ii = 0;
        idx[q] = ii;
    }
    __syncthreads();
    size_t base = (size_t)b * 2500 * 256;
    size_t co = base + (size_t)t * 256 + q;
    float center = h2f(H0[co]) + h2f(H1[co]);
    float mx = -INFINITY;
    for (int kk = 0; kk < k; kk++) {
        size_t no = base + (size_t)idx[kk] * 256 + q;
        float v = h2f(H0[no]) + h2f(H1[no]);
        mx = fmaxf(mx, v - center);
    }
    unsigned short c0 = f2h(center), d0 = f2h(mx);
    unsigned short c1 = f2h(center - h2f(c0)), d1 = f2h(mx - h2f(d0));
    size_t fo = (size_t)b * 2500 * 256 + (size_t)t * 256 + q;  // u32 pair index
    ((unsigned*)F0)[fo] = (unsigned)c0 | ((unsigned)d0 << 16);
    ((unsigned*)F1)[fo] = (unsigned)c1 | ((unsigned)d1 << 16);
}

// ---------------------------------------------------------------------------
// Final transpose: out[b][c][t] = reconstruct(X planes)
// ---------------------------------------------------------------------------
__global__ __launch_bounds__(256)
void outt_k(const unsigned short* __restrict__ X0, const unsigned short* __restrict__ X1,
            float* __restrict__ out)
{
    __shared__ float tile[64][65];
    int t0 = blockIdx.x * 64, c0 = blockIdx.y * 64, b = blockIdx.z;
    int tid = threadIdx.x;
    int tl = tid & 63;
#pragma unroll
    for (int p = 0; p < 16; p++) {
        int tt = (tid >> 6) + p * 4;
        int t = t0 + tt;
        int tc = (t < 2500) ? t : 2499;
        size_t off = ((size_t)b * 2500 + tc) * 256 + c0 + tl;
        tile[tl][tt] = h2f(X0[off]) + h2f(X1[off]);
    }
    __syncthreads();
#pragma unroll
    for (int p = 0; p < 16; p++) {
        int cc = (tid >> 6) + p * 4;
        int t = t0 + tl;
        if (t < 2500)
            out[((size_t)b * 256 + c0 + cc) * 2500 + t] = tile[cc][tl];
    }
}

// ---------------------------------------------------------------------------
extern "C" void kernel_launch(void* const* d_in, const int* in_sizes, int n_in,
                              void* d_out, int out_size, void* d_ws, size_t ws_size,
                              hipStream_t stream)
{
    (void)in_sizes; (void)n_in; (void)out_size; (void)ws_size;
    const float* x_in = (const float*)d_in[0];
    const float *swp[5], *sbp[5], *sgp[5], *sbep[5];
    for (int i = 0; i < 5; i++) {
        swp[i] = (const float*)d_in[1 + 4 * i];
        sbp[i] = (const float*)d_in[2 + 4 * i];
        sgp[i] = (const float*)d_in[3 + 4 * i];
        sbep[i] = (const float*)d_in[4 + 4 * i];
    }
    const float* fc1_w = (const float*)d_in[21];
    const float* fc1_b = (const float*)d_in[22];
    const float* fc1_g = (const float*)d_in[23];
    const float* fc1_be = (const float*)d_in[24];
    const float* mr_w = (const float*)d_in[25];
    const float* mr_g = (const float*)d_in[26];
    const float* mr_be = (const float*)d_in[27];
    const float* fc2_w = (const float*)d_in[28];
    const float* fc2_b = (const float*)d_in[29];
    const float* fc2_g = (const float*)d_in[30];
    const float* fc2_be = (const float*)d_in[31];
    const float* ffn1_w = (const float*)d_in[32];
    const float* ffn1_b = (const float*)d_in[33];
    const float* ffn1_g = (const float*)d_in[34];
    const float* ffn1_be = (const float*)d_in[35];
    const float* ffn2_w = (const float*)d_in[36];
    const float* ffn2_b = (const float*)d_in[37];
    const float* ffn2_g = (const float*)d_in[38];
    const float* ffn2_be = (const float*)d_in[39];

    float* ws = (float*)d_ws;
    // ---- workspace layout (float units; r6-proven offsets, 2 planes used) ----
    const size_t NEG_F = 1920000;
    const size_t G_F   = 3840000;
    const size_t TI_F  = 3000000;      // stem-only, dead by main loop
    const size_t CW_F  = 10300000;
    const size_t X_F   = 12500000;
    const size_t HF_F  = 14420000;
    const size_t W_F   = 16340000;
    const size_t SQ_F  = 17815000;
    const size_t PART_F = 17820000;
    const size_t FIN_F = 17829000;
    const size_t IDX_F = 17830000;

    float* ping = ws;
    float* pong = ws + X_F;
    float* NEG  = ws + NEG_F;
    unsigned short* HT0 = (unsigned short*)ws;            // HT planes
    unsigned short* HT1 = HT0 + 1280000;
    unsigned short* Fp0 = (unsigned short*)ws;            // F planes
    unsigned short* Fp1 = Fp0 + 2560000;
    unsigned short* Gp0 = (unsigned short*)(ws + G_F);    // G planes
    unsigned short* Gp1 = Gp0 + 2560000;
    unsigned short* H20 = (unsigned short*)ws;            // HF2 planes
    unsigned short* H21 = H20 + 5120000;
    unsigned short* TI0 = (unsigned short*)(ws + TI_F);   // stem split-T planes
    unsigned short* CW0 = (unsigned short*)(ws + CW_F);
    unsigned short* X0 = (unsigned short*)(ws + X_F);
    unsigned short* X1 = X0 + 1280000;
    unsigned short* HF0 = (unsigned short*)(ws + HF_F);
    unsigned short* HF1 = HF0 + 1280000;
    unsigned short* W0 = (unsigned short*)(ws + W_F);
    unsigned short* W1 = W0 + 983040;
    float* SQ = ws + SQ_F;
    double* PART = (double*)(ws + PART_F);
    float* FIN = ws + FIN_F;
    int* IDX = (int*)(ws + IDX_F);

    // ---------------- stem ----------------
    int Co[5] = {32, 64, 128, 256, 256};
    int Ho[5] = {400, 200, 100, 50, 50};
    int Ssub[5] = {8, 8, 4, 2, 2};
    float* cur = nullptr;
    for (int l = 0; l < 5; l++) {
        float* outb = (l % 2 == 0) ? ping : pong;
        int HWo = Ho[l] * Ho[l];
        switch (l) {
        case 0:
            conv3x3_t<3, 32><<<dim3(628, 1, 2), 256, 0, stream>>>(
                x_in, swp[0], sbp[0], outb, 32, 800, 800, 400, 400, 2);
            break;
        case 1:
            conv3x3_t<32, 32><<<dim3(160, 2, 2), 256, 0, stream>>>(
                cur, swp[1], sbp[1], outb, 64, 400, 400, 200, 200, 2);
            break;
        case 2:
            conv3x3_t<64, 16><<<dim3(40, 8, 2), 256, 0, stream>>>(
                cur, swp[2], sbp[2], outb, 128, 200, 200, 100, 100, 2);
            break;
        case 3: {
            int psz = 2 * 10000 * 128;
            splitT_k<<<dim3(157, 2, 2), 256, 0, stream>>>(
                cur, TI0, TI0 + psz, 128, 10000);
            int tot = 256 * 1152;
            wconvp_k<<<(tot + 255) / 256, 256, 0, stream>>>(
                swp[3], CW0, CW0 + tot, 128, tot);
            mconv3h_k<128><<<dim3(40, 4, 2), 256, 0, stream>>>(
                TI0, TI0 + psz, CW0, CW0 + tot,
                sbp[3], outb, 256, 100, 100, 50, 50, 2);
            break;
        }
        case 4: {
            int psz = 2 * 2500 * 256;
            splitT_k<<<dim3(40, 4, 2), 256, 0, stream>>>(
                cur, TI0, TI0 + psz, 256, 2500);
            int tot = 256 * 2304;
            wconvp_k<<<(tot + 255) / 256, 256, 0, stream>>>(
                swp[4], CW0, CW0 + tot, 256, tot);
            mconv3h_k<256><<<dim3(40, 4, 2), 256, 0, stream>>>(
                TI0, TI0 + psz, CW0, CW0 + tot,
                sbp[4], outb, 256, 50, 50, 50, 50, 1);
            break;
        }
        }
        int cpg = Co[l] / 32;
        gn_stats_k<<<dim3(Ssub[l], 32, 2), 256, 0, stream>>>(outb, PART, Co[l], HWo, cpg, Ssub[l]);
        gn_reduce_k<<<1, 64, 0, stream>>>(PART, FIN, Ssub[l], (double)cpg * (double)HWo);
        int total = 2 * Co[l] * HWo;
        gn_apply_k<<<(total + 255) / 256, 256, 0, stream>>>(outb, FIN, sgp[l], sbep[l],
                                                            Co[l], HWo, cpg, (l < 4) ? 1 : 0, total);
        cur = outb;
    }
    posadd_k<<<dim3(40, 4, 2), 256, 0, stream>>>(cur, X0, X1);

    // ---------------- 12 Grapher + FFN blocks ----------------
    const int KS[12] = {9, 9, 10, 11, 12, 13, 13, 14, 15, 16, 17, 18};
    const int DILS[12] = {1, 1, 1, 1, 2, 2, 2, 2, 3, 3, 3, 3};
    const int D = 256, N = 2500;

    for (int i = 0; i < 12; i++) {
        pack5p_k<<<3840, 256, 0, stream>>>(
            fc1_w + (size_t)i * 65536, mr_w + (size_t)i * 262144,
            fc2_w + (size_t)i * 131072, ffn1_w + (size_t)i * 262144,
            ffn2_w + (size_t)i * 262144, W0, W1);

        // fc1 -> HF planes
        mgemm3h_k<2><<<dim3(40, 4, 2), 256, 0, stream>>>(
            X0, X1, W0, W1,
            fc1_b + i * D, fc1_g + i * D, fc1_be + i * D,
            nullptr, nullptr, HF0, HF1, N, D, D, 0);
        tok_k<<<dim3(625, 2), 256, 0, stream>>>(HF0, HF1, HT0, HT1, SQ);
        for (int bz = 0; bz < 2; bz++) {
            mdist3h_k<<<dim3(820, 1, 1), 256, 0, stream>>>(HT0, HT1, SQ, NEG, N, D, bz);
            topk_k<<<dim3(1250, 1, 1), 128, 0, stream>>>(NEG, IDX, N,
                                                         KS[i] * DILS[i], DILS[i], KS[i], bz);
        }
        gather_k<<<dim3(2500, 2), 256, 0, stream>>>(HF0, HF1, IDX, Fp0, Fp1, KS[i]);
        // mr -> G planes
        mgemm3h_k<4><<<dim3(40, 4, 2), 256, 0, stream>>>(
            Fp0, Fp1, W0 + 65536, W1 + 65536,
            nullptr, mr_g + i * 512, mr_be + i * 512,
            nullptr, nullptr, Gp0, Gp1, N, 512, 512, 1);
        // fc2 + residual -> X planes
        mgemm3h_k<2><<<dim3(40, 4, 2), 256, 0, stream>>>(
            Gp0, Gp1, W0 + 327680, W1 + 327680,
            fc2_b + i * D, fc2_g + i * D, fc2_be + i * D,
            X0, X1, X0, X1, N, D, 512, 0);
        // ffn1 -> HF2 planes
        mgemm3h_k<4><<<dim3(40, 8, 2), 256, 0, stream>>>(
            X0, X1, W0 + 458752, W1 + 458752,
            ffn1_b + i * 1024, ffn1_g + i * 1024, ffn1_be + i * 1024,
            nullptr, nullptr, H20, H21, N, 1024, D, 1);
        // ffn2 + residual -> X planes
        mgemm3h_k<2><<<dim3(40, 4, 2), 256, 0, stream>>>(
            H20, H21, W0 + 720896, W1 + 720896,
            ffn2_b + i * D, ffn2_g + i * D, ffn2_be + i * D,
            X0, X1, X0, X1, N, D, 1024, 0);
    }

    outt_k<<<dim3(40, 4, 2), 256, 0, stream>>>(X0, X1, (float*)d_out);
}